// Round 10
// baseline (582.421 us; speedup 1.0000x reference)
//
#include <hip/hip_runtime.h>
#include <math.h>

#define NN 20000
#define NE 320000
#define CC 10000
#define KIN 768
#define NH 8
#define ND 64
#define NHD 512
#define NSA 128
#define NBKT 79                 // buckets of 256 nodes: 79*256 = 20224 >= NN

#define WTB_SZ (NHD * KIN)      // 393216 per graph
#define W1TB_SZ (NSA * NHD)     // 65536 per stage

typedef __attribute__((ext_vector_type(4))) float f32x4;
typedef __attribute__((ext_vector_type(8))) short s16x8;

__device__ __forceinline__ unsigned short f2bf(float f) {
  unsigned u = __float_as_uint(f);
  u += 0x7fffu + ((u >> 16) & 1u);
  return (unsigned short)(u >> 16);
}
__device__ __forceinline__ float bf2f(unsigned short s) {
  return __uint_as_float(((unsigned)s) << 16);
}
__device__ __forceinline__ float bflo(unsigned u) { return __uint_as_float(u << 16); }
__device__ __forceinline__ float bfhi(unsigned u) { return __uint_as_float(u & 0xffff0000u); }

__device__ __forceinline__ void gl_lds16(const void* g, void* l) {
  __builtin_amdgcn_global_load_lds(
      (const __attribute__((address_space(1))) unsigned int*)g,
      (__attribute__((address_space(3))) unsigned int*)l, 16, 0, 0);
}

// ---------------- prep: all weight transposes + zero deg3 + zero scal ----------------
__global__ void k_prep(const float* __restrict__ W0, const float* __restrict__ W1,
                       const float* __restrict__ W2, const float* __restrict__ sw1,
                       const float* __restrict__ aw1, unsigned short* __restrict__ wtb3,
                       unsigned short* __restrict__ w1tb2, int* __restrict__ deg3,
                       float* __restrict__ scal) {
  int i = blockIdx.x * 256 + threadIdx.x;
  if (i < 3 * WTB_SZ) {
    int g = i / WTB_SZ;
    int j = i - g * WTB_SZ;
    int n = j / KIN, k = j - n * KIN;
    const float* W = (g == 0) ? W0 : (g == 1) ? W1 : W2;
    wtb3[i] = f2bf(W[(size_t)k * NHD + n]);
    return;
  }
  i -= 3 * WTB_SZ;
  if (i < 2 * W1TB_SZ) {
    int p = i / W1TB_SZ;
    int j = i - p * W1TB_SZ;
    int n = j / NHD, k = j - n * NHD;
    const float* W = p ? aw1 : sw1;
    w1tb2[p * W1TB_SZ + n * NHD + k] = f2bf(W[(size_t)k * NSA + n]);
    return;
  }
  i -= 2 * W1TB_SZ;
  if (i < 3 * NN) { deg3[i] = 0; return; }
  i -= 3 * NN;
  if (i < 4) scal[i] = 0.f;
}

// ---------------- cast feat ----------------
__global__ void k_cast_feat(const float* __restrict__ s, unsigned short* __restrict__ d, int n4) {
  int i = blockIdx.x * 256 + threadIdx.x;
  if (i >= n4) return;
  float4 v = ((const float4*)s)[i];
  ushort4 o;
  o.x = f2bf(v.x); o.y = f2bf(v.y); o.z = f2bf(v.z); o.w = f2bf(v.w);
  ((ushort4*)d)[i] = o;
}

// ---------------- GAT GEMM: hb[M,512](bf16) = A[M,768](bf16) @ Wt[512,768]^T ----------------
// Fused epilogue: el_t[h][row] = sum_d h*al, er_t likewise (each wave owns complete
// (row, head) column sets: head = (col0+wc)>>6).
__global__ __launch_bounds__(256, 2) void k_gemm_gat(const unsigned short* __restrict__ A,
                                                     const unsigned short* __restrict__ Bt,
                                                     unsigned short* __restrict__ outb,
                                                     const float* __restrict__ al,
                                                     const float* __restrict__ ar,
                                                     float* __restrict__ el_t,
                                                     float* __restrict__ er_t) {
  __shared__ unsigned short As[128 * 32];
  __shared__ unsigned short Bs[128 * 32];
  const int tid = threadIdx.x;
  const int wv = tid >> 6, lane = tid & 63;
  const int row0 = blockIdx.x * 128;
  const int col0 = blockIdx.y * 128;
  const int wr = (wv >> 1) * 64, wc = (wv & 1) * 64;
  const int ci = lane & 3, rsub = lane >> 2;

  f32x4 acc[4][4] = {};

  const int l15 = lane & 15;
  const int pc = (((lane >> 4) ^ ((l15 >> 1) & 3))) * 8;

  for (int k0 = 0; k0 < KIN; k0 += 32) {
#pragma unroll
    for (int i = 0; i < 2; i++) {
      int lrow = (wv * 2 + i) * 16 + rsub;
      int kc = (ci ^ ((lrow >> 1) & 3)) << 3;
      int ga = row0 + lrow; if (ga > NN - 1) ga = NN - 1;
      gl_lds16(A + (size_t)ga * KIN + k0 + kc, As + (wv * 2 + i) * 512);
      int gb = col0 + lrow;
      gl_lds16(Bt + (size_t)gb * KIN + k0 + kc, Bs + (wv * 2 + i) * 512);
    }
    __syncthreads();
    s16x8 af[4], bf[4];
#pragma unroll
    for (int m = 0; m < 4; m++) {
      af[m] = *(const s16x8*)(As + (wr + m * 16 + l15) * 32 + pc);
      bf[m] = *(const s16x8*)(Bs + (wc + m * 16 + l15) * 32 + pc);
    }
#pragma unroll
    for (int m = 0; m < 4; m++)
#pragma unroll
      for (int n = 0; n < 4; n++)
        acc[m][n] = __builtin_amdgcn_mfma_f32_16x16x32_bf16(af[m], bf[n], acc[m][n], 0, 0, 0);
    __syncthreads();
  }

  const int cbase = col0 + wc + l15;
  const int rq = (lane >> 4) * 4;
  const int hd = (col0 + wc) >> 6;   // head owned by this wave
  float alc[4], arc[4];
#pragma unroll
  for (int n = 0; n < 4; n++) { alc[n] = al[cbase + n * 16]; arc[n] = ar[cbase + n * 16]; }

#pragma unroll
  for (int m = 0; m < 4; m++) {
#pragma unroll
    for (int r = 0; r < 4; r++) {
      int grow = row0 + wr + m * 16 + rq + r;
      float a = 0.f, b = 0.f;
#pragma unroll
      for (int n = 0; n < 4; n++) {
        float v = acc[m][n][r];
        a += v * alc[n];
        b += v * arc[n];
      }
      a += __shfl_xor(a, 1, 64); a += __shfl_xor(a, 2, 64);
      a += __shfl_xor(a, 4, 64); a += __shfl_xor(a, 8, 64);
      b += __shfl_xor(b, 1, 64); b += __shfl_xor(b, 2, 64);
      b += __shfl_xor(b, 4, 64); b += __shfl_xor(b, 8, 64);
      if (grow < NN) {
        unsigned short* dp = outb + (size_t)grow * NHD + cbase;
#pragma unroll
        for (int n = 0; n < 4; n++) dp[n * 16] = f2bf(acc[m][n][r]);
        if (l15 == 0) {
          el_t[hd * NN + grow] = a;
          er_t[hd * NN + grow] = b;
        }
      }
    }
  }
}

// ---------------- semantic GEMM with fused tanh*w2 row-reduce ----------------
__global__ __launch_bounds__(256, 2) void k_gemm_sem(const unsigned short* __restrict__ A,
                                                     const unsigned short* __restrict__ Bt,
                                                     const float* __restrict__ b1,
                                                     const float* __restrict__ w2,
                                                     float* __restrict__ scal,
                                                     int M, int K) {
  __shared__ unsigned short As[128 * 32];
  __shared__ unsigned short Bs[128 * 32];
  __shared__ float rsum[2][128];
  __shared__ float pp[2][2];
  const int tid = threadIdx.x;
  const int wv = tid >> 6, lane = tid & 63;
  const int row0 = blockIdx.x * 128;
  const int wr = (wv >> 1) * 64, wc = (wv & 1) * 64;
  const int ci = lane & 3, rsub = lane >> 2;

  f32x4 acc[4][4] = {};

  const int l15 = lane & 15;
  const int pc = (((lane >> 4) ^ ((l15 >> 1) & 3))) * 8;

  for (int k0 = 0; k0 < K; k0 += 32) {
#pragma unroll
    for (int i = 0; i < 2; i++) {
      int lrow = (wv * 2 + i) * 16 + rsub;
      int kc = (ci ^ ((lrow >> 1) & 3)) << 3;
      int ga = row0 + lrow; if (ga > M - 1) ga = M - 1;
      gl_lds16(A + (size_t)ga * K + k0 + kc, As + (wv * 2 + i) * 512);
      int gb = lrow;  // col0 = 0, Nb = 128
      gl_lds16(Bt + (size_t)gb * K + k0 + kc, Bs + (wv * 2 + i) * 512);
    }
    __syncthreads();
    s16x8 af[4], bf[4];
#pragma unroll
    for (int m = 0; m < 4; m++) {
      af[m] = *(const s16x8*)(As + (wr + m * 16 + l15) * 32 + pc);
      bf[m] = *(const s16x8*)(Bs + (wc + m * 16 + l15) * 32 + pc);
    }
#pragma unroll
    for (int m = 0; m < 4; m++)
#pragma unroll
      for (int n = 0; n < 4; n++)
        acc[m][n] = __builtin_amdgcn_mfma_f32_16x16x32_bf16(af[m], bf[n], acc[m][n], 0, 0, 0);
    __syncthreads();
  }

  if (tid < 128) { rsum[0][tid] = 0.f; rsum[1][tid] = 0.f; }
  __syncthreads();
  const int cb = wc + l15;
  const int rq = (lane >> 4) * 4;
  float b1c[4], w2c[4];
#pragma unroll
  for (int n = 0; n < 4; n++) { b1c[n] = b1[cb + n * 16]; w2c[n] = w2[cb + n * 16]; }
#pragma unroll
  for (int m = 0; m < 4; m++) {
#pragma unroll
    for (int r = 0; r < 4; r++) {
      int rl = wr + m * 16 + rq + r;
      float s = 0.f;
#pragma unroll
      for (int n = 0; n < 4; n++) s += tanhf(acc[m][n][r] + b1c[n]) * w2c[n];
      s += __shfl_xor(s, 1, 64); s += __shfl_xor(s, 2, 64);
      s += __shfl_xor(s, 4, 64); s += __shfl_xor(s, 8, 64);
      if (l15 == 0 && row0 + rl < M) rsum[wv & 1][rl] = s;
    }
  }
  __syncthreads();
  if (tid < 128) {
    int grow = row0 + tid;
    float v = rsum[0][tid] + rsum[1][tid];
    float vA = (grow < CC) ? v : 0.f;
    float vB = (grow >= CC && grow < M) ? v : 0.f;
#pragma unroll
    for (int off = 32; off > 0; off >>= 1) {
      vA += __shfl_xor(vA, off, 64);
      vB += __shfl_xor(vB, off, 64);
    }
    if ((tid & 63) == 0) { pp[tid >> 6][0] = vA; pp[tid >> 6][1] = vB; }
  }
  __syncthreads();
  if (tid == 0) {
    atomicAdd(scal + 0, pp[0][0] + pp[1][0]);
    atomicAdd(scal + 1, pp[0][1] + pp[1][1]);
  }
}

// ---------------- batched CSR build (3 graphs), bucket-staged scatter ----------------
__global__ void k_hist3(const int* __restrict__ d0, const int* __restrict__ d1,
                        const int* __restrict__ d2, int* __restrict__ deg3) {
  int e = blockIdx.x * 256 + threadIdx.x;
  int g = blockIdx.y;
  const int* dst = (g == 0) ? d0 : (g == 1) ? d1 : d2;
  atomicAdd(deg3 + g * NN + dst[e], 1);
}

__global__ __launch_bounds__(1024) void k_scan3(const int* __restrict__ deg3,
                                                int* __restrict__ rowptr3,
                                                int* __restrict__ curB) {
  __shared__ int part[1024];
  const int g = blockIdx.x;
  const int* deg = deg3 + g * NN;
  int* rowptr = rowptr3 + g * (NN + 1);
  int tid = threadIdx.x;
  const int CH = 20;
  int base = tid * CH;
  int s = 0;
  for (int i = 0; i < CH; i++) { int idx = base + i; if (idx < NN) s += deg[idx]; }
  part[tid] = s;
  __syncthreads();
  for (int off = 1; off < 1024; off <<= 1) {
    int u = (tid >= off) ? part[tid - off] : 0;
    int v = part[tid];
    __syncthreads();
    part[tid] = u + v;
    __syncthreads();
  }
  int run = (tid == 0) ? 0 : part[tid - 1];
  for (int i = 0; i < CH; i++) {
    int idx = base + i;
    if (idx < NN) {
      rowptr[idx] = run;
      if ((idx & 255) == 0) curB[g * (NBKT + 1) + (idx >> 8)] = run;
      run += deg[idx];
    }
  }
  if (tid == 1023) rowptr[NN] = part[1023];
}

__global__ __launch_bounds__(1024) void k_coarse(const int* __restrict__ s0,
                                                 const int* __restrict__ s1,
                                                 const int* __restrict__ s2,
                                                 const int* __restrict__ d0,
                                                 const int* __restrict__ d1,
                                                 const int* __restrict__ d2,
                                                 int* __restrict__ curB,
                                                 unsigned* __restrict__ staging) {
  __shared__ int bcnt[NBKT];
  __shared__ int bbase[NBKT];
  int g = blockIdx.y;
  const int* src = (g == 0) ? s0 : (g == 1) ? s1 : s2;
  const int* dst = (g == 0) ? d0 : (g == 1) ? d1 : d2;
  int tid = threadIdx.x;
  if (tid < NBKT) bcnt[tid] = 0;
  __syncthreads();
  int e = blockIdx.x * 1024 + tid;
  bool val = e < NE;
  int b = 0, r = 0, sv = 0, dv = 0;
  if (val) {
    dv = dst[e]; sv = src[e];
    b = dv >> 8;
    r = atomicAdd(&bcnt[b], 1);
  }
  __syncthreads();
  if (tid < NBKT && bcnt[tid] > 0) bbase[tid] = atomicAdd(&curB[g * (NBKT + 1) + tid], bcnt[tid]);
  __syncthreads();
  if (val) staging[(size_t)g * NE + bbase[b] + r] = ((unsigned)sv << 8) | (unsigned)(dv & 255);
}

__global__ __launch_bounds__(1024) void k_fine(const int* __restrict__ rowptr3,
                                               const unsigned* __restrict__ staging,
                                               unsigned short* __restrict__ srcord3) {
  __shared__ int cur[256];
  int g = blockIdx.y, b = blockIdx.x;
  const int* rowptr = rowptr3 + g * (NN + 1);
  int n0 = b << 8;
  int tid = threadIdx.x;
  if (tid < 256) {
    int node = n0 + tid;
    cur[tid] = (node < NN) ? rowptr[node] : 0;
  }
  __syncthreads();
  int nend = n0 + 256; if (nend > NN) nend = NN;
  int start = rowptr[n0];
  int endp = rowptr[nend];
  for (int i = start + tid; i < endp; i += 1024) {
    unsigned u = staging[(size_t)g * NE + i];
    int nl = u & 255;
    int pos = atomicAdd(&cur[nl], 1);
    srcord3[(size_t)g * NE + pos] = (unsigned short)(u >> 8);
  }
}

// ---------------- SLICED softmax + gather aggregation + bias + elu + z ----------------
// slice s = blockIdx.x % 8 == head s (64 cols). Round-robin blockIdx->XCD pins all
// slice-s blocks to XCD s, whose hb working set (20000 x 128B = 2.56 MB) is L2-resident.
// Wave per (node, slice); lane = (e8 = lane>>3 edge slot, c8 = lane&7 col chunk).
__global__ __launch_bounds__(256) void k_aggs(const int* __restrict__ rowptr,
                                              const unsigned short* __restrict__ srcord,
                                              const float* __restrict__ el_t,
                                              const float* __restrict__ er_t,
                                              const unsigned short* __restrict__ hb,
                                              const float* __restrict__ bias,
                                              float* __restrict__ o,
                                              unsigned short* __restrict__ zb) {
  __shared__ float aS[4][64];
  __shared__ unsigned short sS[4][64];
  int bid = blockIdx.x;
  int s = bid & 7;                      // slice == head, pinned to one XCD
  int wv = threadIdx.x >> 6;
  int t = (bid >> 3) * 4 + wv;          // node (grid exact: NN/4*8 blocks)
  int lane = threadIdx.x & 63;
  int e8 = lane >> 3, c8 = lane & 7;
  int beg = rowptr[t], end = rowptr[t + 1];
  float ers = er_t[s * NN + t];
  const float* els = el_t + s * NN;

  float acc[8] = {0.f, 0.f, 0.f, 0.f, 0.f, 0.f, 0.f, 0.f};
  float den = 0.f;
  const unsigned short* hbs = hb + s * 64 + c8 * 8;

  for (int cbeg = beg; cbeg < end; cbeg += 64) {
    int cnt = end - cbeg; if (cnt > 64) cnt = 64;
    int pidx = cbeg + lane; if (pidx > end - 1) pidx = end - 1;
    int sv = srcord[pidx];
    sS[wv][lane] = (unsigned short)sv;
    float w = 0.f;
    if (lane < cnt) {
      float x = els[sv] + ers;
      x = x >= 0.f ? x : 0.2f * x;
      w = __expf(x);
    }
    aS[wv][lane] = w;
    int iters = (cnt + 7) >> 3;
    for (int it = 0; it < iters; it++) {
      int q = it * 8 + e8;
      float wq = aS[wv][q];
      int sq = sS[wv][q];
      uint4 v = *(const uint4*)(hbs + (size_t)sq * NHD);
      den += wq;
      acc[0] += wq * bflo(v.x); acc[1] += wq * bfhi(v.x);
      acc[2] += wq * bflo(v.y); acc[3] += wq * bfhi(v.y);
      acc[4] += wq * bflo(v.z); acc[5] += wq * bfhi(v.z);
      acc[6] += wq * bflo(v.w); acc[7] += wq * bfhi(v.w);
    }
  }

  // reduce across the 8 edge-slots (strides 8,16,32 keep c8 fixed)
#pragma unroll
  for (int off = 8; off < 64; off <<= 1) {
    den += __shfl_xor(den, off, 64);
#pragma unroll
    for (int j = 0; j < 8; j++) acc[j] += __shfl_xor(acc[j], off, 64);
  }

  if (e8 == 0) {
    float dn = 1.f / fmaxf(den, 1e-9f);
    int colb = s * 64 + c8 * 8;
    float4 b0 = ((const float4*)(bias + colb))[0];
    float4 b1 = ((const float4*)(bias + colb))[1];
    float r[8];
    r[0] = acc[0] * dn + b0.x; r[1] = acc[1] * dn + b0.y;
    r[2] = acc[2] * dn + b0.z; r[3] = acc[3] * dn + b0.w;
    r[4] = acc[4] * dn + b1.x; r[5] = acc[5] * dn + b1.y;
    r[6] = acc[6] * dn + b1.z; r[7] = acc[7] * dn + b1.w;
#pragma unroll
    for (int j = 0; j < 8; j++) r[j] = r[j] > 0.f ? r[j] : expm1f(r[j]);
    float* op = o + (size_t)t * NHD + colb;
    ((float4*)op)[0] = make_float4(r[0], r[1], r[2], r[3]);
    ((float4*)op)[1] = make_float4(r[4], r[5], r[6], r[7]);
    if (t < CC) {
      uint4 z;
      z.x = ((unsigned)f2bf(r[1]) << 16) | f2bf(r[0]);
      z.y = ((unsigned)f2bf(r[3]) << 16) | f2bf(r[2]);
      z.z = ((unsigned)f2bf(r[5]) << 16) | f2bf(r[4]);
      z.w = ((unsigned)f2bf(r[7]) << 16) | f2bf(r[6]);
      *(uint4*)(zb + (size_t)t * NHD + colb) = z;
    }
  }
}

// stage 1: out(bf16 zcat front) = beta0*zA + beta1*zB   (zA,zB f32)
__global__ void k_combine_s1(const float* __restrict__ scal, const float* __restrict__ zA,
                             const float* __restrict__ zB, unsigned short* __restrict__ outb) {
  int i = blockIdx.x * 256 + threadIdx.x;
  float w0 = scal[0] * (1.f / CC), w1v = scal[1] * (1.f / CC);
  float mx = fmaxf(w0, w1v);
  float e0 = expf(w0 - mx), e1 = expf(w1v - mx);
  float inv = 1.f / (e0 + e1);
  float b0 = e0 * inv, b1v = e1 * inv;
  float4 a = ((const float4*)zA)[i];
  float4 b = ((const float4*)zB)[i];
  ushort4 z;
  z.x = f2bf(b0 * a.x + b1v * b.x);
  z.y = f2bf(b0 * a.y + b1v * b.y);
  z.z = f2bf(b0 * a.z + b1v * b.z);
  z.w = f2bf(b0 * a.w + b1v * b.w);
  ((ushort4*)outb)[i] = z;
}

// ---------------- fused stage-2 combine + final head-means ----------------
__global__ void k_comb2_means(const float* __restrict__ scal,
                              const unsigned short* __restrict__ zsound,
                              const float* __restrict__ o0, const float* __restrict__ o1,
                              const float* __restrict__ o2, float* __restrict__ outf,
                              float* __restrict__ m1, float* __restrict__ m2,
                              float* __restrict__ m3) {
  int idx = blockIdx.x * 256 + threadIdx.x;   // grid exact NN*64
  int n = idx >> 6, d = idx & 63;
  if (n < CC) {
    float w0 = scal[0] * (1.f / CC), w1v = scal[1] * (1.f / CC);
    float mx = fmaxf(w0, w1v);
    float e0 = expf(w0 - mx), e1 = expf(w1v - mx);
    float inv = 1.f / (e0 + e1);
    float b0 = e0 * inv, b1v = e1 * inv;
    const unsigned short* zs = zsound + (size_t)n * NHD + d;
    const float* p1 = o1 + (size_t)n * NHD + d;
    float* po = outf + (size_t)n * NHD + d;
    float v = 0.f;
#pragma unroll
    for (int h = 0; h < 8; h++) {
      float r = b0 * bf2f(zs[h * 64]) + b1v * p1[h * 64];
      po[h * 64] = r;
      v += r;
    }
    v *= 0.125f;
    m1[idx] = v; m2[idx] = v; m3[idx] = v;
  } else {
    const float* p0 = o0 + (size_t)n * NHD + d;
    const float* p1 = o1 + (size_t)n * NHD + d;
    const float* p2 = o2 + (size_t)n * NHD + d;
    float v0 = 0.f, v1 = 0.f, v2 = 0.f;
#pragma unroll
    for (int h = 0; h < 8; h++) { v0 += p0[h * 64]; v1 += p1[h * 64]; v2 += p2[h * 64]; }
    m1[idx] = v0 * 0.125f; m2[idx] = v1 * 0.125f; m3[idx] = v2 * 0.125f;
  }
}

extern "C" void kernel_launch(void* const* d_in, const int* in_sizes, int n_in,
                              void* d_out, int out_size, void* d_ws, size_t ws_size,
                              hipStream_t stream) {
  (void)in_sizes; (void)n_in; (void)out_size; (void)ws_size;

  const float* feat[3]; const int* srcp[3]; const int* dstp[3];
  const float* Wp[3]; const float* alp[3]; const float* arp[3]; const float* bp[3];
  for (int g = 0; g < 3; g++) {
    const int base = g * 8;  // dict order: feat,src,dst,char,W,al,ar,b
    feat[g] = (const float*)d_in[base + 0];
    srcp[g] = (const int*)d_in[base + 1];
    dstp[g] = (const int*)d_in[base + 2];
    Wp[g]   = (const float*)d_in[base + 4];
    alp[g]  = (const float*)d_in[base + 5];
    arp[g]  = (const float*)d_in[base + 6];
    bp[g]   = (const float*)d_in[base + 7];
  }
  const float* sw1 = (const float*)d_in[24];
  const float* sb1 = (const float*)d_in[25];
  const float* sw2 = (const float*)d_in[26];
  const float* aw1 = (const float*)d_in[27];
  const float* ab1 = (const float*)d_in[28];
  const float* aw2 = (const float*)d_in[29];

  char* wsp = (char*)d_ws;
  auto alloc = [&](size_t bytes) {
    char* p = wsp;
    wsp += (bytes + 255) & ~(size_t)255;
    return p;
  };
  float* o0 = (float*)alloc((size_t)NN * NHD * 4);
  float* o1 = (float*)alloc((size_t)NN * NHD * 4);
  float* o2 = (float*)alloc((size_t)NN * NHD * 4);
  unsigned short* hb = (unsigned short*)alloc((size_t)NN * NHD * 2);
  unsigned short* featb = (unsigned short*)alloc((size_t)NN * KIN * 2);
  unsigned short* wtb3 = (unsigned short*)alloc((size_t)3 * WTB_SZ * 2);
  unsigned short* w1tb2 = (unsigned short*)alloc((size_t)2 * W1TB_SZ * 2);
  unsigned short* zcat = (unsigned short*)alloc((size_t)2 * CC * NHD * 2);
  float* el_t = (float*)alloc((size_t)NN * NH * 4);
  float* er_t = (float*)alloc((size_t)NN * NH * 4);
  float* scal = (float*)alloc(256);
  int* deg3 = (int*)alloc((size_t)3 * NN * 4);
  int* rowptr3 = (int*)alloc((size_t)3 * (NN + 1) * 4 + 64);
  int* curB = (int*)alloc((size_t)3 * (NBKT + 1) * 4);
  unsigned* staging = (unsigned*)alloc((size_t)3 * NE * 4);
  unsigned short* srcord3 = (unsigned short*)alloc((size_t)3 * NE * 2);

  float* outf = (float*)d_out;
  float* outm1 = outf + (size_t)CC * NHD;
  float* outm2 = outm1 + (size_t)NN * ND;
  float* outm3 = outm2 + (size_t)NN * ND;

  // ---- prep: weight transposes + zero deg3/scal; bucket-staged CSR build ----
  const int PREP_T = 3 * WTB_SZ + 2 * W1TB_SZ + 3 * NN + 4;
  k_prep<<<(PREP_T + 255) / 256, 256, 0, stream>>>(Wp[0], Wp[1], Wp[2], sw1, aw1,
                                                   wtb3, w1tb2, deg3, scal);
  k_hist3<<<dim3(NE / 256, 3), 256, 0, stream>>>(dstp[0], dstp[1], dstp[2], deg3);
  k_scan3<<<3, 1024, 0, stream>>>(deg3, rowptr3, curB);
  k_coarse<<<dim3((NE + 1023) / 1024, 3), 1024, 0, stream>>>(
      srcp[0], srcp[1], srcp[2], dstp[0], dstp[1], dstp[2], curB, staging);
  k_fine<<<dim3(NBKT, 3), 1024, 0, stream>>>(rowptr3, staging, srcord3);

  // one full GAT layer for metapath g; emits bf16 C-rows into zb
  auto gat = [&](int g, float* og, unsigned short* zb) {
    k_cast_feat<<<NN * KIN / 4 / 256, 256, 0, stream>>>(feat[g], featb, NN * KIN / 4);
    k_gemm_gat<<<dim3((NN + 127) / 128, NHD / 128), 256, 0, stream>>>(
        featb, wtb3 + (size_t)g * WTB_SZ, hb, alp[g], arp[g], el_t, er_t);
    k_aggs<<<NN * 8 / 4, 256, 0, stream>>>(rowptr3 + g * (NN + 1), srcord3 + (size_t)g * NE,
                                           el_t, er_t, hb, bp[g], og, zb);
  };

  // metapaths 0 and 2 fill zcat = [h1[0:C] ; hh[0:C]] (bf16)
  gat(0, o0, zcat);
  gat(2, o2, zcat + (size_t)CC * NHD);

  // ---- semantic stage 1: fused gemm+reduce; combine writes bf16 sound into zcat front ----
  k_gemm_sem<<<(2 * CC + 127) / 128, 256, 0, stream>>>(zcat, w1tb2, sb1, sw2, scal, 2 * CC, NHD);
  k_combine_s1<<<CC * NHD / 4 / 256, 256, 0, stream>>>(scal, o0, o2, zcat);

  // metapath 1 fills zcat back half -> zcat = [sound ; h2[0:C]]
  gat(1, o1, zcat + (size_t)CC * NHD);

  // ---- semantic stage 2: fused gemm+reduce -> combine+means into d_out ----
  k_gemm_sem<<<(2 * CC + 127) / 128, 256, 0, stream>>>(zcat, w1tb2 + W1TB_SZ, ab1, aw2,
                                                       scal + 2, 2 * CC, NHD);
  k_comb2_means<<<NN * 64 / 256, 256, 0, stream>>>(scal + 2, zcat, o0, o1, o2,
                                                   outf, outm1, outm2, outm3);
}

// Round 11
// 488.601 us; speedup vs baseline: 1.1920x; 1.1920x over previous
//
#include <hip/hip_runtime.h>
#include <math.h>

#define NN 20000
#define NE 320000
#define CC 10000
#define KIN 768
#define NH 8
#define ND 64
#define NHD 512
#define NSA 128
#define NBKT 79                 // buckets of 256 nodes: 79*256 = 20224 >= NN

#define WTB_SZ (NHD * KIN)      // 393216 per graph
#define W1TB_SZ (NSA * NHD)     // 65536 per stage

typedef __attribute__((ext_vector_type(4))) float f32x4;
typedef __attribute__((ext_vector_type(8))) short s16x8;

__device__ __forceinline__ unsigned short f2bf(float f) {
  unsigned u = __float_as_uint(f);
  u += 0x7fffu + ((u >> 16) & 1u);
  return (unsigned short)(u >> 16);
}
__device__ __forceinline__ float bf2f(unsigned short s) {
  return __uint_as_float(((unsigned)s) << 16);
}
__device__ __forceinline__ float bflo(unsigned u) { return __uint_as_float(u << 16); }
__device__ __forceinline__ float bfhi(unsigned u) { return __uint_as_float(u & 0xffff0000u); }

__device__ __forceinline__ void gl_lds16(const void* g, void* l) {
  __builtin_amdgcn_global_load_lds(
      (const __attribute__((address_space(1))) unsigned int*)g,
      (__attribute__((address_space(3))) unsigned int*)l, 16, 0, 0);
}

// ---------------- prep: all weight transposes + zero deg3 + zero scal ----------------
__global__ void k_prep(const float* __restrict__ W0, const float* __restrict__ W1,
                       const float* __restrict__ W2, const float* __restrict__ sw1,
                       const float* __restrict__ aw1, unsigned short* __restrict__ wtb3,
                       unsigned short* __restrict__ w1tb2, int* __restrict__ deg3,
                       float* __restrict__ scal) {
  int i = blockIdx.x * 256 + threadIdx.x;
  if (i < 3 * WTB_SZ) {
    int g = i / WTB_SZ;
    int j = i - g * WTB_SZ;
    int n = j / KIN, k = j - n * KIN;
    const float* W = (g == 0) ? W0 : (g == 1) ? W1 : W2;
    wtb3[i] = f2bf(W[(size_t)k * NHD + n]);
    return;
  }
  i -= 3 * WTB_SZ;
  if (i < 2 * W1TB_SZ) {
    int p = i / W1TB_SZ;
    int j = i - p * W1TB_SZ;
    int n = j / NHD, k = j - n * NHD;
    const float* W = p ? aw1 : sw1;
    w1tb2[p * W1TB_SZ + n * NHD + k] = f2bf(W[(size_t)k * NSA + n]);
    return;
  }
  i -= 2 * W1TB_SZ;
  if (i < 3 * NN) { deg3[i] = 0; return; }
  i -= 3 * NN;
  if (i < 4) scal[i] = 0.f;
}

// ---------------- cast feat ----------------
__global__ void k_cast_feat(const float* __restrict__ s, unsigned short* __restrict__ d, int n4) {
  int i = blockIdx.x * 256 + threadIdx.x;
  if (i >= n4) return;
  float4 v = ((const float4*)s)[i];
  ushort4 o;
  o.x = f2bf(v.x); o.y = f2bf(v.y); o.z = f2bf(v.z); o.w = f2bf(v.w);
  ((ushort4*)d)[i] = o;
}

// ---------------- GAT GEMM: hb[M,512](bf16) = A[M,768](bf16) @ Wt[512,768]^T ----------------
// Fused epilogue: el[row*NH+h] = sum_d h*al, er likewise (each wave owns complete
// (row, head) column sets: head = (col0+wc)>>6). Node-major layout for k_aggf.
__global__ __launch_bounds__(256, 2) void k_gemm_gat(const unsigned short* __restrict__ A,
                                                     const unsigned short* __restrict__ Bt,
                                                     unsigned short* __restrict__ outb,
                                                     const float* __restrict__ al,
                                                     const float* __restrict__ ar,
                                                     float* __restrict__ el,
                                                     float* __restrict__ er) {
  __shared__ unsigned short As[128 * 32];
  __shared__ unsigned short Bs[128 * 32];
  const int tid = threadIdx.x;
  const int wv = tid >> 6, lane = tid & 63;
  const int row0 = blockIdx.x * 128;
  const int col0 = blockIdx.y * 128;
  const int wr = (wv >> 1) * 64, wc = (wv & 1) * 64;
  const int ci = lane & 3, rsub = lane >> 2;

  f32x4 acc[4][4] = {};

  const int l15 = lane & 15;
  const int pc = (((lane >> 4) ^ ((l15 >> 1) & 3))) * 8;

  for (int k0 = 0; k0 < KIN; k0 += 32) {
#pragma unroll
    for (int i = 0; i < 2; i++) {
      int lrow = (wv * 2 + i) * 16 + rsub;
      int kc = (ci ^ ((lrow >> 1) & 3)) << 3;
      int ga = row0 + lrow; if (ga > NN - 1) ga = NN - 1;
      gl_lds16(A + (size_t)ga * KIN + k0 + kc, As + (wv * 2 + i) * 512);
      int gb = col0 + lrow;
      gl_lds16(Bt + (size_t)gb * KIN + k0 + kc, Bs + (wv * 2 + i) * 512);
    }
    __syncthreads();
    s16x8 af[4], bf[4];
#pragma unroll
    for (int m = 0; m < 4; m++) {
      af[m] = *(const s16x8*)(As + (wr + m * 16 + l15) * 32 + pc);
      bf[m] = *(const s16x8*)(Bs + (wc + m * 16 + l15) * 32 + pc);
    }
#pragma unroll
    for (int m = 0; m < 4; m++)
#pragma unroll
      for (int n = 0; n < 4; n++)
        acc[m][n] = __builtin_amdgcn_mfma_f32_16x16x32_bf16(af[m], bf[n], acc[m][n], 0, 0, 0);
    __syncthreads();
  }

  const int cbase = col0 + wc + l15;
  const int rq = (lane >> 4) * 4;
  const int hd = (col0 + wc) >> 6;   // head owned by this wave
  float alc[4], arc[4];
#pragma unroll
  for (int n = 0; n < 4; n++) { alc[n] = al[cbase + n * 16]; arc[n] = ar[cbase + n * 16]; }

#pragma unroll
  for (int m = 0; m < 4; m++) {
#pragma unroll
    for (int r = 0; r < 4; r++) {
      int grow = row0 + wr + m * 16 + rq + r;
      float a = 0.f, b = 0.f;
#pragma unroll
      for (int n = 0; n < 4; n++) {
        float v = acc[m][n][r];
        a += v * alc[n];
        b += v * arc[n];
      }
      a += __shfl_xor(a, 1, 64); a += __shfl_xor(a, 2, 64);
      a += __shfl_xor(a, 4, 64); a += __shfl_xor(a, 8, 64);
      b += __shfl_xor(b, 1, 64); b += __shfl_xor(b, 2, 64);
      b += __shfl_xor(b, 4, 64); b += __shfl_xor(b, 8, 64);
      if (grow < NN) {
        unsigned short* dp = outb + (size_t)grow * NHD + cbase;
#pragma unroll
        for (int n = 0; n < 4; n++) dp[n * 16] = f2bf(acc[m][n][r]);
        if (l15 == 0) {
          el[(size_t)grow * NH + hd] = a;
          er[(size_t)grow * NH + hd] = b;
        }
      }
    }
  }
}

// ---------------- semantic GEMM with fused tanh*w2 row-reduce ----------------
__global__ __launch_bounds__(256, 2) void k_gemm_sem(const unsigned short* __restrict__ A,
                                                     const unsigned short* __restrict__ Bt,
                                                     const float* __restrict__ b1,
                                                     const float* __restrict__ w2,
                                                     float* __restrict__ scal,
                                                     int M, int K) {
  __shared__ unsigned short As[128 * 32];
  __shared__ unsigned short Bs[128 * 32];
  __shared__ float rsum[2][128];
  __shared__ float pp[2][2];
  const int tid = threadIdx.x;
  const int wv = tid >> 6, lane = tid & 63;
  const int row0 = blockIdx.x * 128;
  const int wr = (wv >> 1) * 64, wc = (wv & 1) * 64;
  const int ci = lane & 3, rsub = lane >> 2;

  f32x4 acc[4][4] = {};

  const int l15 = lane & 15;
  const int pc = (((lane >> 4) ^ ((l15 >> 1) & 3))) * 8;

  for (int k0 = 0; k0 < K; k0 += 32) {
#pragma unroll
    for (int i = 0; i < 2; i++) {
      int lrow = (wv * 2 + i) * 16 + rsub;
      int kc = (ci ^ ((lrow >> 1) & 3)) << 3;
      int ga = row0 + lrow; if (ga > M - 1) ga = M - 1;
      gl_lds16(A + (size_t)ga * K + k0 + kc, As + (wv * 2 + i) * 512);
      int gb = lrow;  // col0 = 0, Nb = 128
      gl_lds16(Bt + (size_t)gb * K + k0 + kc, Bs + (wv * 2 + i) * 512);
    }
    __syncthreads();
    s16x8 af[4], bf[4];
#pragma unroll
    for (int m = 0; m < 4; m++) {
      af[m] = *(const s16x8*)(As + (wr + m * 16 + l15) * 32 + pc);
      bf[m] = *(const s16x8*)(Bs + (wc + m * 16 + l15) * 32 + pc);
    }
#pragma unroll
    for (int m = 0; m < 4; m++)
#pragma unroll
      for (int n = 0; n < 4; n++)
        acc[m][n] = __builtin_amdgcn_mfma_f32_16x16x32_bf16(af[m], bf[n], acc[m][n], 0, 0, 0);
    __syncthreads();
  }

  if (tid < 128) { rsum[0][tid] = 0.f; rsum[1][tid] = 0.f; }
  __syncthreads();
  const int cb = wc + l15;
  const int rq = (lane >> 4) * 4;
  float b1c[4], w2c[4];
#pragma unroll
  for (int n = 0; n < 4; n++) { b1c[n] = b1[cb + n * 16]; w2c[n] = w2[cb + n * 16]; }
#pragma unroll
  for (int m = 0; m < 4; m++) {
#pragma unroll
    for (int r = 0; r < 4; r++) {
      int rl = wr + m * 16 + rq + r;
      float s = 0.f;
#pragma unroll
      for (int n = 0; n < 4; n++) s += tanhf(acc[m][n][r] + b1c[n]) * w2c[n];
      s += __shfl_xor(s, 1, 64); s += __shfl_xor(s, 2, 64);
      s += __shfl_xor(s, 4, 64); s += __shfl_xor(s, 8, 64);
      if (l15 == 0 && row0 + rl < M) rsum[wv & 1][rl] = s;
    }
  }
  __syncthreads();
  if (tid < 128) {
    int grow = row0 + tid;
    float v = rsum[0][tid] + rsum[1][tid];
    float vA = (grow < CC) ? v : 0.f;
    float vB = (grow >= CC && grow < M) ? v : 0.f;
#pragma unroll
    for (int off = 32; off > 0; off >>= 1) {
      vA += __shfl_xor(vA, off, 64);
      vB += __shfl_xor(vB, off, 64);
    }
    if ((tid & 63) == 0) { pp[tid >> 6][0] = vA; pp[tid >> 6][1] = vB; }
  }
  __syncthreads();
  if (tid == 0) {
    atomicAdd(scal + 0, pp[0][0] + pp[1][0]);
    atomicAdd(scal + 1, pp[0][1] + pp[1][1]);
  }
}

// ---------------- batched CSR build (3 graphs), bucket-staged scatter ----------------
__global__ void k_hist3(const int* __restrict__ d0, const int* __restrict__ d1,
                        const int* __restrict__ d2, int* __restrict__ deg3) {
  int e = blockIdx.x * 256 + threadIdx.x;
  int g = blockIdx.y;
  const int* dst = (g == 0) ? d0 : (g == 1) ? d1 : d2;
  atomicAdd(deg3 + g * NN + dst[e], 1);
}

__global__ __launch_bounds__(1024) void k_scan3(const int* __restrict__ deg3,
                                                int* __restrict__ rowptr3,
                                                int* __restrict__ curB) {
  __shared__ int part[1024];
  const int g = blockIdx.x;
  const int* deg = deg3 + g * NN;
  int* rowptr = rowptr3 + g * (NN + 1);
  int tid = threadIdx.x;
  const int CH = 20;
  int base = tid * CH;
  int s = 0;
  for (int i = 0; i < CH; i++) { int idx = base + i; if (idx < NN) s += deg[idx]; }
  part[tid] = s;
  __syncthreads();
  for (int off = 1; off < 1024; off <<= 1) {
    int u = (tid >= off) ? part[tid - off] : 0;
    int v = part[tid];
    __syncthreads();
    part[tid] = u + v;
    __syncthreads();
  }
  int run = (tid == 0) ? 0 : part[tid - 1];
  for (int i = 0; i < CH; i++) {
    int idx = base + i;
    if (idx < NN) {
      rowptr[idx] = run;
      if ((idx & 255) == 0) curB[g * (NBKT + 1) + (idx >> 8)] = run;
      run += deg[idx];
    }
  }
  if (tid == 1023) rowptr[NN] = part[1023];
}

__global__ __launch_bounds__(1024) void k_coarse(const int* __restrict__ s0,
                                                 const int* __restrict__ s1,
                                                 const int* __restrict__ s2,
                                                 const int* __restrict__ d0,
                                                 const int* __restrict__ d1,
                                                 const int* __restrict__ d2,
                                                 int* __restrict__ curB,
                                                 unsigned* __restrict__ staging) {
  __shared__ int bcnt[NBKT];
  __shared__ int bbase[NBKT];
  int g = blockIdx.y;
  const int* src = (g == 0) ? s0 : (g == 1) ? s1 : s2;
  const int* dst = (g == 0) ? d0 : (g == 1) ? d1 : d2;
  int tid = threadIdx.x;
  if (tid < NBKT) bcnt[tid] = 0;
  __syncthreads();
  int e = blockIdx.x * 1024 + tid;
  bool val = e < NE;
  int b = 0, r = 0, sv = 0, dv = 0;
  if (val) {
    dv = dst[e]; sv = src[e];
    b = dv >> 8;
    r = atomicAdd(&bcnt[b], 1);
  }
  __syncthreads();
  if (tid < NBKT && bcnt[tid] > 0) bbase[tid] = atomicAdd(&curB[g * (NBKT + 1) + tid], bcnt[tid]);
  __syncthreads();
  if (val) staging[(size_t)g * NE + bbase[b] + r] = ((unsigned)sv << 8) | (unsigned)(dv & 255);
}

__global__ __launch_bounds__(1024) void k_fine(const int* __restrict__ rowptr3,
                                               const unsigned* __restrict__ staging,
                                               unsigned short* __restrict__ srcord3) {
  __shared__ int cur[256];
  int g = blockIdx.y, b = blockIdx.x;
  const int* rowptr = rowptr3 + g * (NN + 1);
  int n0 = b << 8;
  int tid = threadIdx.x;
  if (tid < 256) {
    int node = n0 + tid;
    cur[tid] = (node < NN) ? rowptr[node] : 0;
  }
  __syncthreads();
  int nend = n0 + 256; if (nend > NN) nend = NN;
  int start = rowptr[n0];
  int endp = rowptr[nend];
  for (int i = start + tid; i < endp; i += 1024) {
    unsigned u = staging[(size_t)g * NE + i];
    int nl = u & 255;
    int pos = atomicAdd(&cur[nl], 1);
    srcord3[(size_t)g * NE + pos] = (unsigned short)(u >> 8);
  }
}

// ---------------- FUSED softmax + gather aggregation + bias + elu + z ----------------
// wave per node; lane = 16B slice of the 512-wide row, head = lane>>3.
__global__ __launch_bounds__(256) void k_aggf(const int* __restrict__ rowptr,
                                              const unsigned short* __restrict__ srcord,
                                              const float* __restrict__ el,
                                              const float* __restrict__ er,
                                              const unsigned short* __restrict__ hb,
                                              const float* __restrict__ bias,
                                              float* __restrict__ o,
                                              unsigned short* __restrict__ zb) {
  __shared__ float aS[4][64 * 8];
  __shared__ int sS[4][64];
  int wv = threadIdx.x >> 6;
  int t = (blockIdx.x * 256 + threadIdx.x) >> 6;
  int lane = threadIdx.x & 63;
  int h = lane >> 3;
  int beg = rowptr[t], end = rowptr[t + 1];

  float4 er0 = ((const float4*)(er + (size_t)t * NH))[0];
  float4 er1 = ((const float4*)(er + (size_t)t * NH))[1];
  float erow[8] = {er0.x, er0.y, er0.z, er0.w, er1.x, er1.y, er1.z, er1.w};

  float acc[8] = {0.f, 0.f, 0.f, 0.f, 0.f, 0.f, 0.f, 0.f};
  float den = 0.f;

  for (int cbeg = beg; cbeg < end; cbeg += 64) {
    int cnt = end - cbeg; if (cnt > 64) cnt = 64;
    bool valid = lane < cnt;
    int pidx = cbeg + lane; if (pidx > end - 1) pidx = end - 1;
    int s = srcord[pidx];
    if (valid) {
      sS[wv][lane] = s;
      float4 a0 = ((const float4*)(el + (size_t)s * NH))[0];
      float4 a1 = ((const float4*)(el + (size_t)s * NH))[1];
      float v[8] = {a0.x + erow[0], a0.y + erow[1], a0.z + erow[2], a0.w + erow[3],
                    a1.x + erow[4], a1.y + erow[5], a1.z + erow[6], a1.w + erow[7]};
#pragma unroll
      for (int k = 0; k < 8; k++) {
        float x = v[k];
        x = x >= 0.f ? x : 0.2f * x;
        aS[wv][lane * 8 + k] = __expf(x);
      }
    }
    const unsigned short* hbl = hb + lane * 8;
    int q = 0;
    for (; q + 1 < cnt; q += 2) {
      int s0 = sS[wv][q], s1 = sS[wv][q + 1];
      float w0 = aS[wv][q * 8 + h];
      float w1 = aS[wv][(q + 1) * 8 + h];
      uint4 v0 = *(const uint4*)(hbl + (size_t)s0 * NHD);
      uint4 v1 = *(const uint4*)(hbl + (size_t)s1 * NHD);
      den += w0 + w1;
      acc[0] += w0 * bflo(v0.x); acc[1] += w0 * bfhi(v0.x);
      acc[2] += w0 * bflo(v0.y); acc[3] += w0 * bfhi(v0.y);
      acc[4] += w0 * bflo(v0.z); acc[5] += w0 * bfhi(v0.z);
      acc[6] += w0 * bflo(v0.w); acc[7] += w0 * bfhi(v0.w);
      acc[0] += w1 * bflo(v1.x); acc[1] += w1 * bfhi(v1.x);
      acc[2] += w1 * bflo(v1.y); acc[3] += w1 * bfhi(v1.y);
      acc[4] += w1 * bflo(v1.z); acc[5] += w1 * bfhi(v1.z);
      acc[6] += w1 * bflo(v1.w); acc[7] += w1 * bfhi(v1.w);
    }
    if (q < cnt) {
      int s0 = sS[wv][q];
      float w0 = aS[wv][q * 8 + h];
      uint4 v0 = *(const uint4*)(hbl + (size_t)s0 * NHD);
      den += w0;
      acc[0] += w0 * bflo(v0.x); acc[1] += w0 * bfhi(v0.x);
      acc[2] += w0 * bflo(v0.y); acc[3] += w0 * bfhi(v0.y);
      acc[4] += w0 * bflo(v0.z); acc[5] += w0 * bfhi(v0.z);
      acc[6] += w0 * bflo(v0.w); acc[7] += w0 * bfhi(v0.w);
    }
  }

  float dn = 1.f / fmaxf(den, 1e-9f);
  float4 b0 = ((const float4*)(bias + lane * 8))[0];
  float4 b1 = ((const float4*)(bias + lane * 8))[1];
  float r[8];
  r[0] = acc[0] * dn + b0.x; r[1] = acc[1] * dn + b0.y;
  r[2] = acc[2] * dn + b0.z; r[3] = acc[3] * dn + b0.w;
  r[4] = acc[4] * dn + b1.x; r[5] = acc[5] * dn + b1.y;
  r[6] = acc[6] * dn + b1.z; r[7] = acc[7] * dn + b1.w;
#pragma unroll
  for (int j = 0; j < 8; j++) r[j] = r[j] > 0.f ? r[j] : expm1f(r[j]);
  float* op = o + (size_t)t * NHD + lane * 8;
  ((float4*)op)[0] = make_float4(r[0], r[1], r[2], r[3]);
  ((float4*)op)[1] = make_float4(r[4], r[5], r[6], r[7]);
  if (t < CC) {
    uint4 z;
    z.x = ((unsigned)f2bf(r[1]) << 16) | f2bf(r[0]);
    z.y = ((unsigned)f2bf(r[3]) << 16) | f2bf(r[2]);
    z.z = ((unsigned)f2bf(r[5]) << 16) | f2bf(r[4]);
    z.w = ((unsigned)f2bf(r[7]) << 16) | f2bf(r[6]);
    *(uint4*)(zb + (size_t)t * NHD + lane * 8) = z;
  }
}

// stage 1: out(bf16 zcat front) = beta0*zA + beta1*zB   (zA,zB f32)
__global__ void k_combine_s1(const float* __restrict__ scal, const float* __restrict__ zA,
                             const float* __restrict__ zB, unsigned short* __restrict__ outb) {
  int i = blockIdx.x * 256 + threadIdx.x;
  float w0 = scal[0] * (1.f / CC), w1v = scal[1] * (1.f / CC);
  float mx = fmaxf(w0, w1v);
  float e0 = expf(w0 - mx), e1 = expf(w1v - mx);
  float inv = 1.f / (e0 + e1);
  float b0 = e0 * inv, b1v = e1 * inv;
  float4 a = ((const float4*)zA)[i];
  float4 b = ((const float4*)zB)[i];
  ushort4 z;
  z.x = f2bf(b0 * a.x + b1v * b.x);
  z.y = f2bf(b0 * a.y + b1v * b.y);
  z.z = f2bf(b0 * a.z + b1v * b.z);
  z.w = f2bf(b0 * a.w + b1v * b.w);
  ((ushort4*)outb)[i] = z;
}

// ---------------- fused stage-2 combine + final head-means ----------------
__global__ void k_comb2_means(const float* __restrict__ scal,
                              const unsigned short* __restrict__ zsound,
                              const float* __restrict__ o0, const float* __restrict__ o1,
                              const float* __restrict__ o2, float* __restrict__ outf,
                              float* __restrict__ m1, float* __restrict__ m2,
                              float* __restrict__ m3) {
  int idx = blockIdx.x * 256 + threadIdx.x;   // grid exact NN*64
  int n = idx >> 6, d = idx & 63;
  if (n < CC) {
    float w0 = scal[0] * (1.f / CC), w1v = scal[1] * (1.f / CC);
    float mx = fmaxf(w0, w1v);
    float e0 = expf(w0 - mx), e1 = expf(w1v - mx);
    float inv = 1.f / (e0 + e1);
    float b0 = e0 * inv, b1v = e1 * inv;
    const unsigned short* zs = zsound + (size_t)n * NHD + d;
    const float* p1 = o1 + (size_t)n * NHD + d;
    float* po = outf + (size_t)n * NHD + d;
    float v = 0.f;
#pragma unroll
    for (int h = 0; h < 8; h++) {
      float r = b0 * bf2f(zs[h * 64]) + b1v * p1[h * 64];
      po[h * 64] = r;
      v += r;
    }
    v *= 0.125f;
    m1[idx] = v; m2[idx] = v; m3[idx] = v;
  } else {
    const float* p0 = o0 + (size_t)n * NHD + d;
    const float* p1 = o1 + (size_t)n * NHD + d;
    const float* p2 = o2 + (size_t)n * NHD + d;
    float v0 = 0.f, v1 = 0.f, v2 = 0.f;
#pragma unroll
    for (int h = 0; h < 8; h++) { v0 += p0[h * 64]; v1 += p1[h * 64]; v2 += p2[h * 64]; }
    m1[idx] = v0 * 0.125f; m2[idx] = v1 * 0.125f; m3[idx] = v2 * 0.125f;
  }
}

extern "C" void kernel_launch(void* const* d_in, const int* in_sizes, int n_in,
                              void* d_out, int out_size, void* d_ws, size_t ws_size,
                              hipStream_t stream) {
  (void)in_sizes; (void)n_in; (void)out_size; (void)ws_size;

  const float* feat[3]; const int* srcp[3]; const int* dstp[3];
  const float* Wp[3]; const float* alp[3]; const float* arp[3]; const float* bp[3];
  for (int g = 0; g < 3; g++) {
    const int base = g * 8;  // dict order: feat,src,dst,char,W,al,ar,b
    feat[g] = (const float*)d_in[base + 0];
    srcp[g] = (const int*)d_in[base + 1];
    dstp[g] = (const int*)d_in[base + 2];
    Wp[g]   = (const float*)d_in[base + 4];
    alp[g]  = (const float*)d_in[base + 5];
    arp[g]  = (const float*)d_in[base + 6];
    bp[g]   = (const float*)d_in[base + 7];
  }
  const float* sw1 = (const float*)d_in[24];
  const float* sb1 = (const float*)d_in[25];
  const float* sw2 = (const float*)d_in[26];
  const float* aw1 = (const float*)d_in[27];
  const float* ab1 = (const float*)d_in[28];
  const float* aw2 = (const float*)d_in[29];

  char* wsp = (char*)d_ws;
  auto alloc = [&](size_t bytes) {
    char* p = wsp;
    wsp += (bytes + 255) & ~(size_t)255;
    return p;
  };
  float* o0 = (float*)alloc((size_t)NN * NHD * 4);
  float* o1 = (float*)alloc((size_t)NN * NHD * 4);
  float* o2 = (float*)alloc((size_t)NN * NHD * 4);
  unsigned short* hb = (unsigned short*)alloc((size_t)NN * NHD * 2);
  unsigned short* featb = (unsigned short*)alloc((size_t)NN * KIN * 2);
  unsigned short* wtb3 = (unsigned short*)alloc((size_t)3 * WTB_SZ * 2);
  unsigned short* w1tb2 = (unsigned short*)alloc((size_t)2 * W1TB_SZ * 2);
  unsigned short* zcat = (unsigned short*)alloc((size_t)2 * CC * NHD * 2);
  float* el = (float*)alloc((size_t)NN * NH * 4);
  float* er = (float*)alloc((size_t)NN * NH * 4);
  float* scal = (float*)alloc(256);
  int* deg3 = (int*)alloc((size_t)3 * NN * 4);
  int* rowptr3 = (int*)alloc((size_t)3 * (NN + 1) * 4 + 64);
  int* curB = (int*)alloc((size_t)3 * (NBKT + 1) * 4);
  unsigned* staging = (unsigned*)alloc((size_t)3 * NE * 4);
  unsigned short* srcord3 = (unsigned short*)alloc((size_t)3 * NE * 2);

  float* outf = (float*)d_out;
  float* outm1 = outf + (size_t)CC * NHD;
  float* outm2 = outm1 + (size_t)NN * ND;
  float* outm3 = outm2 + (size_t)NN * ND;

  // ---- prep: weight transposes + zero deg3/scal; bucket-staged CSR build ----
  const int PREP_T = 3 * WTB_SZ + 2 * W1TB_SZ + 3 * NN + 4;
  k_prep<<<(PREP_T + 255) / 256, 256, 0, stream>>>(Wp[0], Wp[1], Wp[2], sw1, aw1,
                                                   wtb3, w1tb2, deg3, scal);
  k_hist3<<<dim3(NE / 256, 3), 256, 0, stream>>>(dstp[0], dstp[1], dstp[2], deg3);
  k_scan3<<<3, 1024, 0, stream>>>(deg3, rowptr3, curB);
  k_coarse<<<dim3((NE + 1023) / 1024, 3), 1024, 0, stream>>>(
      srcp[0], srcp[1], srcp[2], dstp[0], dstp[1], dstp[2], curB, staging);
  k_fine<<<dim3(NBKT, 3), 1024, 0, stream>>>(rowptr3, staging, srcord3);

  // one full GAT layer for metapath g; emits bf16 C-rows into zb
  auto gat = [&](int g, float* og, unsigned short* zb) {
    k_cast_feat<<<NN * KIN / 4 / 256, 256, 0, stream>>>(feat[g], featb, NN * KIN / 4);
    k_gemm_gat<<<dim3((NN + 127) / 128, NHD / 128), 256, 0, stream>>>(
        featb, wtb3 + (size_t)g * WTB_SZ, hb, alp[g], arp[g], el, er);
    k_aggf<<<NN * 64 / 256, 256, 0, stream>>>(rowptr3 + g * (NN + 1), srcord3 + (size_t)g * NE,
                                              el, er, hb, bp[g], og, zb);
  };

  // metapaths 0 and 2 fill zcat = [h1[0:C] ; hh[0:C]] (bf16)
  gat(0, o0, zcat);
  gat(2, o2, zcat + (size_t)CC * NHD);

  // ---- semantic stage 1: fused gemm+reduce; combine writes bf16 sound into zcat front ----
  k_gemm_sem<<<(2 * CC + 127) / 128, 256, 0, stream>>>(zcat, w1tb2, sb1, sw2, scal, 2 * CC, NHD);
  k_combine_s1<<<CC * NHD / 4 / 256, 256, 0, stream>>>(scal, o0, o2, zcat);

  // metapath 1 fills zcat back half -> zcat = [sound ; h2[0:C]]
  gat(1, o1, zcat + (size_t)CC * NHD);

  // ---- semantic stage 2: fused gemm+reduce -> combine+means into d_out ----
  k_gemm_sem<<<(2 * CC + 127) / 128, 256, 0, stream>>>(zcat, w1tb2 + W1TB_SZ, ab1, aw2,
                                                       scal + 2, 2 * CC, NHD);
  k_comb2_means<<<NN * 64 / 256, 256, 0, stream>>>(scal + 2, zcat, o0, o1, o2,
                                                   outf, outm1, outm2, outm3);
}

// Round 12
// 460.222 us; speedup vs baseline: 1.2655x; 1.0617x over previous
//
#include <hip/hip_runtime.h>
#include <math.h>

#define NN 20000
#define NE 320000
#define CC 10000
#define KIN 768
#define NH 8
#define ND 64
#define NHD 512
#define NSA 128
#define NBKT 79                 // buckets of 256 nodes: 79*256 = 20224 >= NN

#define WTB_SZ (NHD * KIN)      // 393216 per graph
#define W1TB_SZ (NSA * NHD)     // 65536 per stage
#define FEAT_SZ (NN * KIN)      // per-graph feat elements

typedef __attribute__((ext_vector_type(4))) float f32x4;
typedef __attribute__((ext_vector_type(8))) short s16x8;

__device__ __forceinline__ unsigned short f2bf(float f) {
  unsigned u = __float_as_uint(f);
  u += 0x7fffu + ((u >> 16) & 1u);
  return (unsigned short)(u >> 16);
}
__device__ __forceinline__ float bf2f(unsigned short s) {
  return __uint_as_float(((unsigned)s) << 16);
}
__device__ __forceinline__ float bflo(unsigned u) { return __uint_as_float(u << 16); }
__device__ __forceinline__ float bfhi(unsigned u) { return __uint_as_float(u & 0xffff0000u); }

__device__ __forceinline__ void gl_lds16(const void* g, void* l) {
  __builtin_amdgcn_global_load_lds(
      (const __attribute__((address_space(1))) unsigned int*)g,
      (__attribute__((address_space(3))) unsigned int*)l, 16, 0, 0);
}

// ---------------- prep: all weight transposes + zero deg3 + zero scal ----------------
__global__ void k_prep(const float* __restrict__ W0, const float* __restrict__ W1,
                       const float* __restrict__ W2, const float* __restrict__ sw1,
                       const float* __restrict__ aw1, unsigned short* __restrict__ wtb3,
                       unsigned short* __restrict__ w1tb2, int* __restrict__ deg3,
                       float* __restrict__ scal) {
  int i = blockIdx.x * 256 + threadIdx.x;
  if (i < 3 * WTB_SZ) {
    int g = i / WTB_SZ;
    int j = i - g * WTB_SZ;
    int n = j / KIN, k = j - n * KIN;
    const float* W = (g == 0) ? W0 : (g == 1) ? W1 : W2;
    wtb3[i] = f2bf(W[(size_t)k * NHD + n]);
    return;
  }
  i -= 3 * WTB_SZ;
  if (i < 2 * W1TB_SZ) {
    int p = i / W1TB_SZ;
    int j = i - p * W1TB_SZ;
    int n = j / NHD, k = j - n * NHD;
    const float* W = p ? aw1 : sw1;
    w1tb2[p * W1TB_SZ + n * NHD + k] = f2bf(W[(size_t)k * NSA + n]);
    return;
  }
  i -= 2 * W1TB_SZ;
  if (i < 3 * NN) { deg3[i] = 0; return; }
  i -= 3 * NN;
  if (i < 4) scal[i] = 0.f;
}

// ---------------- cast feat (3 graphs batched) ----------------
__global__ void k_cast_feat3(const float* __restrict__ f0, const float* __restrict__ f1,
                             const float* __restrict__ f2, unsigned short* __restrict__ d3) {
  int i = blockIdx.x * 256 + threadIdx.x;   // grid exact FEAT_SZ/4 per graph
  int g = blockIdx.y;
  const float* s = (g == 0) ? f0 : (g == 1) ? f1 : f2;
  float4 v = ((const float4*)s)[i];
  ushort4 o;
  o.x = f2bf(v.x); o.y = f2bf(v.y); o.z = f2bf(v.z); o.w = f2bf(v.w);
  ((ushort4*)(d3 + (size_t)g * FEAT_SZ))[i] = o;
}

// ---------------- GAT GEMM: hb[M,512](bf16) = A[M,768](bf16) @ Wt[512,768]^T ----------------
// Fused epilogue: el[row*NH+h], er likewise (wave owns complete (row, head) col sets).
__global__ __launch_bounds__(256, 2) void k_gemm_gat(const unsigned short* __restrict__ A,
                                                     const unsigned short* __restrict__ Bt,
                                                     unsigned short* __restrict__ outb,
                                                     const float* __restrict__ al,
                                                     const float* __restrict__ ar,
                                                     float* __restrict__ el,
                                                     float* __restrict__ er) {
  __shared__ unsigned short As[128 * 32];
  __shared__ unsigned short Bs[128 * 32];
  const int tid = threadIdx.x;
  const int wv = tid >> 6, lane = tid & 63;
  const int row0 = blockIdx.x * 128;
  const int col0 = blockIdx.y * 128;
  const int wr = (wv >> 1) * 64, wc = (wv & 1) * 64;
  const int ci = lane & 3, rsub = lane >> 2;

  f32x4 acc[4][4] = {};

  const int l15 = lane & 15;
  const int pc = (((lane >> 4) ^ ((l15 >> 1) & 3))) * 8;

  for (int k0 = 0; k0 < KIN; k0 += 32) {
#pragma unroll
    for (int i = 0; i < 2; i++) {
      int lrow = (wv * 2 + i) * 16 + rsub;
      int kc = (ci ^ ((lrow >> 1) & 3)) << 3;
      int ga = row0 + lrow; if (ga > NN - 1) ga = NN - 1;
      gl_lds16(A + (size_t)ga * KIN + k0 + kc, As + (wv * 2 + i) * 512);
      int gb = col0 + lrow;
      gl_lds16(Bt + (size_t)gb * KIN + k0 + kc, Bs + (wv * 2 + i) * 512);
    }
    __syncthreads();
    s16x8 af[4], bf[4];
#pragma unroll
    for (int m = 0; m < 4; m++) {
      af[m] = *(const s16x8*)(As + (wr + m * 16 + l15) * 32 + pc);
      bf[m] = *(const s16x8*)(Bs + (wc + m * 16 + l15) * 32 + pc);
    }
#pragma unroll
    for (int m = 0; m < 4; m++)
#pragma unroll
      for (int n = 0; n < 4; n++)
        acc[m][n] = __builtin_amdgcn_mfma_f32_16x16x32_bf16(af[m], bf[n], acc[m][n], 0, 0, 0);
    __syncthreads();
  }

  const int cbase = col0 + wc + l15;
  const int rq = (lane >> 4) * 4;
  const int hd = (col0 + wc) >> 6;   // head owned by this wave
  float alc[4], arc[4];
#pragma unroll
  for (int n = 0; n < 4; n++) { alc[n] = al[cbase + n * 16]; arc[n] = ar[cbase + n * 16]; }

#pragma unroll
  for (int m = 0; m < 4; m++) {
#pragma unroll
    for (int r = 0; r < 4; r++) {
      int grow = row0 + wr + m * 16 + rq + r;
      float a = 0.f, b = 0.f;
#pragma unroll
      for (int n = 0; n < 4; n++) {
        float v = acc[m][n][r];
        a += v * alc[n];
        b += v * arc[n];
      }
      a += __shfl_xor(a, 1, 64); a += __shfl_xor(a, 2, 64);
      a += __shfl_xor(a, 4, 64); a += __shfl_xor(a, 8, 64);
      b += __shfl_xor(b, 1, 64); b += __shfl_xor(b, 2, 64);
      b += __shfl_xor(b, 4, 64); b += __shfl_xor(b, 8, 64);
      if (grow < NN) {
        unsigned short* dp = outb + (size_t)grow * NHD + cbase;
#pragma unroll
        for (int n = 0; n < 4; n++) dp[n * 16] = f2bf(acc[m][n][r]);
        if (l15 == 0) {
          el[(size_t)grow * NH + hd] = a;
          er[(size_t)grow * NH + hd] = b;
        }
      }
    }
  }
}

// ---------------- semantic GEMM with fused tanh*w2 row-reduce ----------------
// A rows: row<CC from A0[row], else A1[row-CC]. Accumulates scal[0]/scal[1].
__global__ __launch_bounds__(256, 2) void k_gemm_sem(const unsigned short* __restrict__ A0,
                                                     const unsigned short* __restrict__ A1,
                                                     const unsigned short* __restrict__ Bt,
                                                     const float* __restrict__ b1,
                                                     const float* __restrict__ w2,
                                                     float* __restrict__ scal) {
  __shared__ unsigned short As[128 * 32];
  __shared__ unsigned short Bs[128 * 32];
  __shared__ float rsum[2][128];
  __shared__ float pp[2][2];
  const int M = 2 * CC;
  const int tid = threadIdx.x;
  const int wv = tid >> 6, lane = tid & 63;
  const int row0 = blockIdx.x * 128;
  const int wr = (wv >> 1) * 64, wc = (wv & 1) * 64;
  const int ci = lane & 3, rsub = lane >> 2;

  f32x4 acc[4][4] = {};

  const int l15 = lane & 15;
  const int pc = (((lane >> 4) ^ ((l15 >> 1) & 3))) * 8;

  for (int k0 = 0; k0 < NHD; k0 += 32) {
#pragma unroll
    for (int i = 0; i < 2; i++) {
      int lrow = (wv * 2 + i) * 16 + rsub;
      int kc = (ci ^ ((lrow >> 1) & 3)) << 3;
      int ga = row0 + lrow; if (ga > M - 1) ga = M - 1;
      const unsigned short* Ap = (ga < CC) ? A0 + (size_t)ga * NHD
                                           : A1 + (size_t)(ga - CC) * NHD;
      gl_lds16(Ap + k0 + kc, As + (wv * 2 + i) * 512);
      int gb = lrow;  // col0 = 0, Nb = 128
      gl_lds16(Bt + (size_t)gb * NHD + k0 + kc, Bs + (wv * 2 + i) * 512);
    }
    __syncthreads();
    s16x8 af[4], bf[4];
#pragma unroll
    for (int m = 0; m < 4; m++) {
      af[m] = *(const s16x8*)(As + (wr + m * 16 + l15) * 32 + pc);
      bf[m] = *(const s16x8*)(Bs + (wc + m * 16 + l15) * 32 + pc);
    }
#pragma unroll
    for (int m = 0; m < 4; m++)
#pragma unroll
      for (int n = 0; n < 4; n++)
        acc[m][n] = __builtin_amdgcn_mfma_f32_16x16x32_bf16(af[m], bf[n], acc[m][n], 0, 0, 0);
    __syncthreads();
  }

  if (tid < 128) { rsum[0][tid] = 0.f; rsum[1][tid] = 0.f; }
  __syncthreads();
  const int cb = wc + l15;
  const int rq = (lane >> 4) * 4;
  float b1c[4], w2c[4];
#pragma unroll
  for (int n = 0; n < 4; n++) { b1c[n] = b1[cb + n * 16]; w2c[n] = w2[cb + n * 16]; }
#pragma unroll
  for (int m = 0; m < 4; m++) {
#pragma unroll
    for (int r = 0; r < 4; r++) {
      int rl = wr + m * 16 + rq + r;
      float s = 0.f;
#pragma unroll
      for (int n = 0; n < 4; n++) s += tanhf(acc[m][n][r] + b1c[n]) * w2c[n];
      s += __shfl_xor(s, 1, 64); s += __shfl_xor(s, 2, 64);
      s += __shfl_xor(s, 4, 64); s += __shfl_xor(s, 8, 64);
      if (l15 == 0 && row0 + rl < M) rsum[wv & 1][rl] = s;
    }
  }
  __syncthreads();
  if (tid < 128) {
    int grow = row0 + tid;
    float v = rsum[0][tid] + rsum[1][tid];
    float vA = (grow < CC) ? v : 0.f;
    float vB = (grow >= CC && grow < M) ? v : 0.f;
#pragma unroll
    for (int off = 32; off > 0; off >>= 1) {
      vA += __shfl_xor(vA, off, 64);
      vB += __shfl_xor(vB, off, 64);
    }
    if ((tid & 63) == 0) { pp[tid >> 6][0] = vA; pp[tid >> 6][1] = vB; }
  }
  __syncthreads();
  if (tid == 0) {
    atomicAdd(scal + 0, pp[0][0] + pp[1][0]);
    atomicAdd(scal + 1, pp[0][1] + pp[1][1]);
  }
}

// ---------------- batched CSR build (3 graphs), bucket-staged scatter ----------------
__global__ void k_hist3(const int* __restrict__ d0, const int* __restrict__ d1,
                        const int* __restrict__ d2, int* __restrict__ deg3) {
  int e = blockIdx.x * 256 + threadIdx.x;
  int g = blockIdx.y;
  const int* dst = (g == 0) ? d0 : (g == 1) ? d1 : d2;
  atomicAdd(deg3 + g * NN + dst[e], 1);
}

__global__ __launch_bounds__(1024) void k_scan3(const int* __restrict__ deg3,
                                                int* __restrict__ rowptr3,
                                                int* __restrict__ curB) {
  __shared__ int part[1024];
  const int g = blockIdx.x;
  const int* deg = deg3 + g * NN;
  int* rowptr = rowptr3 + g * (NN + 1);
  int tid = threadIdx.x;
  const int CH = 20;
  int base = tid * CH;
  int s = 0;
  for (int i = 0; i < CH; i++) { int idx = base + i; if (idx < NN) s += deg[idx]; }
  part[tid] = s;
  __syncthreads();
  for (int off = 1; off < 1024; off <<= 1) {
    int u = (tid >= off) ? part[tid - off] : 0;
    int v = part[tid];
    __syncthreads();
    part[tid] = u + v;
    __syncthreads();
  }
  int run = (tid == 0) ? 0 : part[tid - 1];
  for (int i = 0; i < CH; i++) {
    int idx = base + i;
    if (idx < NN) {
      rowptr[idx] = run;
      if ((idx & 255) == 0) curB[g * (NBKT + 1) + (idx >> 8)] = run;
      run += deg[idx];
    }
  }
  if (tid == 1023) rowptr[NN] = part[1023];
}

__global__ __launch_bounds__(1024) void k_coarse(const int* __restrict__ s0,
                                                 const int* __restrict__ s1,
                                                 const int* __restrict__ s2,
                                                 const int* __restrict__ d0,
                                                 const int* __restrict__ d1,
                                                 const int* __restrict__ d2,
                                                 int* __restrict__ curB,
                                                 unsigned* __restrict__ staging) {
  __shared__ int bcnt[NBKT];
  __shared__ int bbase[NBKT];
  int g = blockIdx.y;
  const int* src = (g == 0) ? s0 : (g == 1) ? s1 : s2;
  const int* dst = (g == 0) ? d0 : (g == 1) ? d1 : d2;
  int tid = threadIdx.x;
  if (tid < NBKT) bcnt[tid] = 0;
  __syncthreads();
  int e = blockIdx.x * 1024 + tid;
  bool val = e < NE;
  int b = 0, r = 0, sv = 0, dv = 0;
  if (val) {
    dv = dst[e]; sv = src[e];
    b = dv >> 8;
    r = atomicAdd(&bcnt[b], 1);
  }
  __syncthreads();
  if (tid < NBKT && bcnt[tid] > 0) bbase[tid] = atomicAdd(&curB[g * (NBKT + 1) + tid], bcnt[tid]);
  __syncthreads();
  if (val) staging[(size_t)g * NE + bbase[b] + r] = ((unsigned)sv << 8) | (unsigned)(dv & 255);
}

__global__ __launch_bounds__(1024) void k_fine(const int* __restrict__ rowptr3,
                                               const unsigned* __restrict__ staging,
                                               unsigned short* __restrict__ srcord3) {
  __shared__ int cur[256];
  int g = blockIdx.y, b = blockIdx.x;
  const int* rowptr = rowptr3 + g * (NN + 1);
  int n0 = b << 8;
  int tid = threadIdx.x;
  if (tid < 256) {
    int node = n0 + tid;
    cur[tid] = (node < NN) ? rowptr[node] : 0;
  }
  __syncthreads();
  int nend = n0 + 256; if (nend > NN) nend = NN;
  int start = rowptr[n0];
  int endp = rowptr[nend];
  for (int i = start + tid; i < endp; i += 1024) {
    unsigned u = staging[(size_t)g * NE + i];
    int nl = u & 255;
    int pos = atomicAdd(&cur[nl], 1);
    srcord3[(size_t)g * NE + pos] = (unsigned short)(u >> 8);
  }
}

// ---------------- FUSED softmax + gather aggregation + bias + elu (bf16 out) ----------------
// wave per node; lane = 16B slice of the 512-wide row, head = lane>>3.
__global__ __launch_bounds__(256) void k_aggf(const int* __restrict__ rowptr,
                                              const unsigned short* __restrict__ srcord,
                                              const float* __restrict__ el,
                                              const float* __restrict__ er,
                                              const unsigned short* __restrict__ hb,
                                              const float* __restrict__ bias,
                                              unsigned short* __restrict__ ob) {
  __shared__ float aS[4][64 * 8];
  __shared__ int sS[4][64];
  int wv = threadIdx.x >> 6;
  int t = (blockIdx.x * 256 + threadIdx.x) >> 6;
  int lane = threadIdx.x & 63;
  int h = lane >> 3;
  int beg = rowptr[t], end = rowptr[t + 1];

  float4 er0 = ((const float4*)(er + (size_t)t * NH))[0];
  float4 er1 = ((const float4*)(er + (size_t)t * NH))[1];
  float erow[8] = {er0.x, er0.y, er0.z, er0.w, er1.x, er1.y, er1.z, er1.w};

  float acc[8] = {0.f, 0.f, 0.f, 0.f, 0.f, 0.f, 0.f, 0.f};
  float den = 0.f;

  for (int cbeg = beg; cbeg < end; cbeg += 64) {
    int cnt = end - cbeg; if (cnt > 64) cnt = 64;
    bool valid = lane < cnt;
    int pidx = cbeg + lane; if (pidx > end - 1) pidx = end - 1;
    int s = srcord[pidx];
    if (valid) {
      sS[wv][lane] = s;
      float4 a0 = ((const float4*)(el + (size_t)s * NH))[0];
      float4 a1 = ((const float4*)(el + (size_t)s * NH))[1];
      float v[8] = {a0.x + erow[0], a0.y + erow[1], a0.z + erow[2], a0.w + erow[3],
                    a1.x + erow[4], a1.y + erow[5], a1.z + erow[6], a1.w + erow[7]};
#pragma unroll
      for (int k = 0; k < 8; k++) {
        float x = v[k];
        x = x >= 0.f ? x : 0.2f * x;
        aS[wv][lane * 8 + k] = __expf(x);
      }
    }
    const unsigned short* hbl = hb + lane * 8;
    int q = 0;
    for (; q + 3 < cnt; q += 4) {
      int s0 = sS[wv][q], s1 = sS[wv][q + 1], s2 = sS[wv][q + 2], s3 = sS[wv][q + 3];
      float w0 = aS[wv][q * 8 + h];
      float w1 = aS[wv][(q + 1) * 8 + h];
      float w2 = aS[wv][(q + 2) * 8 + h];
      float w3 = aS[wv][(q + 3) * 8 + h];
      uint4 v0 = *(const uint4*)(hbl + (size_t)s0 * NHD);
      uint4 v1 = *(const uint4*)(hbl + (size_t)s1 * NHD);
      uint4 v2 = *(const uint4*)(hbl + (size_t)s2 * NHD);
      uint4 v3 = *(const uint4*)(hbl + (size_t)s3 * NHD);
      den += (w0 + w1) + (w2 + w3);
      acc[0] += w0 * bflo(v0.x); acc[1] += w0 * bfhi(v0.x);
      acc[2] += w0 * bflo(v0.y); acc[3] += w0 * bfhi(v0.y);
      acc[4] += w0 * bflo(v0.z); acc[5] += w0 * bfhi(v0.z);
      acc[6] += w0 * bflo(v0.w); acc[7] += w0 * bfhi(v0.w);
      acc[0] += w1 * bflo(v1.x); acc[1] += w1 * bfhi(v1.x);
      acc[2] += w1 * bflo(v1.y); acc[3] += w1 * bfhi(v1.y);
      acc[4] += w1 * bflo(v1.z); acc[5] += w1 * bfhi(v1.z);
      acc[6] += w1 * bflo(v1.w); acc[7] += w1 * bfhi(v1.w);
      acc[0] += w2 * bflo(v2.x); acc[1] += w2 * bfhi(v2.x);
      acc[2] += w2 * bflo(v2.y); acc[3] += w2 * bfhi(v2.y);
      acc[4] += w2 * bflo(v2.z); acc[5] += w2 * bfhi(v2.z);
      acc[6] += w2 * bflo(v2.w); acc[7] += w2 * bfhi(v2.w);
      acc[0] += w3 * bflo(v3.x); acc[1] += w3 * bfhi(v3.x);
      acc[2] += w3 * bflo(v3.y); acc[3] += w3 * bfhi(v3.y);
      acc[4] += w3 * bflo(v3.z); acc[5] += w3 * bfhi(v3.z);
      acc[6] += w3 * bflo(v3.w); acc[7] += w3 * bfhi(v3.w);
    }
    for (; q < cnt; q++) {
      int s0 = sS[wv][q];
      float w0 = aS[wv][q * 8 + h];
      uint4 v0 = *(const uint4*)(hbl + (size_t)s0 * NHD);
      den += w0;
      acc[0] += w0 * bflo(v0.x); acc[1] += w0 * bfhi(v0.x);
      acc[2] += w0 * bflo(v0.y); acc[3] += w0 * bfhi(v0.y);
      acc[4] += w0 * bflo(v0.z); acc[5] += w0 * bfhi(v0.z);
      acc[6] += w0 * bflo(v0.w); acc[7] += w0 * bfhi(v0.w);
    }
  }

  float dn = 1.f / fmaxf(den, 1e-9f);
  float4 b0 = ((const float4*)(bias + lane * 8))[0];
  float4 b1 = ((const float4*)(bias + lane * 8))[1];
  float r[8];
  r[0] = acc[0] * dn + b0.x; r[1] = acc[1] * dn + b0.y;
  r[2] = acc[2] * dn + b0.z; r[3] = acc[3] * dn + b0.w;
  r[4] = acc[4] * dn + b1.x; r[5] = acc[5] * dn + b1.y;
  r[6] = acc[6] * dn + b1.z; r[7] = acc[7] * dn + b1.w;
#pragma unroll
  for (int j = 0; j < 8; j++) r[j] = r[j] > 0.f ? r[j] : expm1f(r[j]);
  uint4 z;
  z.x = ((unsigned)f2bf(r[1]) << 16) | f2bf(r[0]);
  z.y = ((unsigned)f2bf(r[3]) << 16) | f2bf(r[2]);
  z.z = ((unsigned)f2bf(r[5]) << 16) | f2bf(r[4]);
  z.w = ((unsigned)f2bf(r[7]) << 16) | f2bf(r[6]);
  *(uint4*)(ob + (size_t)t * NHD + lane * 8) = z;
}

// stage 1: sound(bf16) = beta0*zA(bf16) + beta1*zB(bf16), C*NHD/8 elems per thread-8
__global__ void k_combine_s1(const float* __restrict__ scal,
                             const unsigned short* __restrict__ zA,
                             const unsigned short* __restrict__ zB,
                             unsigned short* __restrict__ outb) {
  int i = blockIdx.x * 256 + threadIdx.x;   // grid exact CC*NHD/4
  float w0 = scal[0] * (1.f / CC), w1v = scal[1] * (1.f / CC);
  float mx = fmaxf(w0, w1v);
  float e0 = expf(w0 - mx), e1 = expf(w1v - mx);
  float inv = 1.f / (e0 + e1);
  float b0 = e0 * inv, b1v = e1 * inv;
  ushort4 a = ((const ushort4*)zA)[i];
  ushort4 b = ((const ushort4*)zB)[i];
  ushort4 z;
  z.x = f2bf(b0 * bf2f(a.x) + b1v * bf2f(b.x));
  z.y = f2bf(b0 * bf2f(a.y) + b1v * bf2f(b.y));
  z.z = f2bf(b0 * bf2f(a.z) + b1v * bf2f(b.z));
  z.w = f2bf(b0 * bf2f(a.w) + b1v * bf2f(b.w));
  ((ushort4*)outb)[i] = z;
}

// ---------------- fused stage-2 combine + final head-means (bf16 inputs) ----------------
__global__ void k_comb2_means(const float* __restrict__ scal,
                              const unsigned short* __restrict__ zsound,
                              const unsigned short* __restrict__ ob0,
                              const unsigned short* __restrict__ ob1,
                              const unsigned short* __restrict__ ob2,
                              float* __restrict__ outf,
                              float* __restrict__ m1, float* __restrict__ m2,
                              float* __restrict__ m3) {
  int idx = blockIdx.x * 256 + threadIdx.x;   // grid exact NN*64
  int n = idx >> 6, d = idx & 63;
  if (n < CC) {
    float w0 = scal[0] * (1.f / CC), w1v = scal[1] * (1.f / CC);
    float mx = fmaxf(w0, w1v);
    float e0 = expf(w0 - mx), e1 = expf(w1v - mx);
    float inv = 1.f / (e0 + e1);
    float b0 = e0 * inv, b1v = e1 * inv;
    const unsigned short* zs = zsound + (size_t)n * NHD + d;
    const unsigned short* p1 = ob1 + (size_t)n * NHD + d;
    float* po = outf + (size_t)n * NHD + d;
    float v = 0.f;
#pragma unroll
    for (int h = 0; h < 8; h++) {
      float r = b0 * bf2f(zs[h * 64]) + b1v * bf2f(p1[h * 64]);
      po[h * 64] = r;
      v += r;
    }
    v *= 0.125f;
    m1[idx] = v; m2[idx] = v; m3[idx] = v;
  } else {
    const unsigned short* p0 = ob0 + (size_t)n * NHD + d;
    const unsigned short* p1 = ob1 + (size_t)n * NHD + d;
    const unsigned short* p2 = ob2 + (size_t)n * NHD + d;
    float v0 = 0.f, v1 = 0.f, v2 = 0.f;
#pragma unroll
    for (int h = 0; h < 8; h++) {
      v0 += bf2f(p0[h * 64]); v1 += bf2f(p1[h * 64]); v2 += bf2f(p2[h * 64]);
    }
    m1[idx] = v0 * 0.125f; m2[idx] = v1 * 0.125f; m3[idx] = v2 * 0.125f;
  }
}

extern "C" void kernel_launch(void* const* d_in, const int* in_sizes, int n_in,
                              void* d_out, int out_size, void* d_ws, size_t ws_size,
                              hipStream_t stream) {
  (void)in_sizes; (void)n_in; (void)out_size; (void)ws_size;

  const float* feat[3]; const int* srcp[3]; const int* dstp[3];
  const float* Wp[3]; const float* alp[3]; const float* arp[3]; const float* bp[3];
  for (int g = 0; g < 3; g++) {
    const int base = g * 8;  // dict order: feat,src,dst,char,W,al,ar,b
    feat[g] = (const float*)d_in[base + 0];
    srcp[g] = (const int*)d_in[base + 1];
    dstp[g] = (const int*)d_in[base + 2];
    Wp[g]   = (const float*)d_in[base + 4];
    alp[g]  = (const float*)d_in[base + 5];
    arp[g]  = (const float*)d_in[base + 6];
    bp[g]   = (const float*)d_in[base + 7];
  }
  const float* sw1 = (const float*)d_in[24];
  const float* sb1 = (const float*)d_in[25];
  const float* sw2 = (const float*)d_in[26];
  const float* aw1 = (const float*)d_in[27];
  const float* ab1 = (const float*)d_in[28];
  const float* aw2 = (const float*)d_in[29];

  char* wsp = (char*)d_ws;
  auto alloc = [&](size_t bytes) {
    char* p = wsp;
    wsp += (bytes + 255) & ~(size_t)255;
    return p;
  };
  // total ~195 MB (proven-safe budget is >=229 MB from round 2)
  unsigned short* ob0 = (unsigned short*)alloc((size_t)NN * NHD * 2);   // 20.5 MB
  unsigned short* ob1 = (unsigned short*)alloc((size_t)NN * NHD * 2);   // 20.5 MB
  unsigned short* ob2 = (unsigned short*)alloc((size_t)NN * NHD * 2);   // 20.5 MB
  unsigned short* hb = (unsigned short*)alloc((size_t)NN * NHD * 2);    // 20.5 MB
  unsigned short* featb3 = (unsigned short*)alloc((size_t)3 * FEAT_SZ * 2); // 92.2 MB
  unsigned short* wtb3 = (unsigned short*)alloc((size_t)3 * WTB_SZ * 2);
  unsigned short* w1tb2 = (unsigned short*)alloc((size_t)2 * W1TB_SZ * 2);
  unsigned short* sound = (unsigned short*)alloc((size_t)CC * NHD * 2); // 10.2 MB
  float* el = (float*)alloc((size_t)NN * NH * 4);
  float* er = (float*)alloc((size_t)NN * NH * 4);
  float* scal = (float*)alloc(256);
  int* deg3 = (int*)alloc((size_t)3 * NN * 4);
  int* rowptr3 = (int*)alloc((size_t)3 * (NN + 1) * 4 + 64);
  int* curB = (int*)alloc((size_t)3 * (NBKT + 1) * 4);
  unsigned* staging = (unsigned*)alloc((size_t)3 * NE * 4);
  unsigned short* srcord3 = (unsigned short*)alloc((size_t)3 * NE * 2);

  float* outf = (float*)d_out;
  float* outm1 = outf + (size_t)CC * NHD;
  float* outm2 = outm1 + (size_t)NN * ND;
  float* outm3 = outm2 + (size_t)NN * ND;

  // ---- prep: weight transposes + zero deg3/scal; feat casts; CSR build ----
  const int PREP_T = 3 * WTB_SZ + 2 * W1TB_SZ + 3 * NN + 4;
  k_prep<<<(PREP_T + 255) / 256, 256, 0, stream>>>(Wp[0], Wp[1], Wp[2], sw1, aw1,
                                                   wtb3, w1tb2, deg3, scal);
  k_cast_feat3<<<dim3(FEAT_SZ / 4 / 256, 3), 256, 0, stream>>>(feat[0], feat[1], feat[2], featb3);
  k_hist3<<<dim3(NE / 256, 3), 256, 0, stream>>>(dstp[0], dstp[1], dstp[2], deg3);
  k_scan3<<<3, 1024, 0, stream>>>(deg3, rowptr3, curB);
  k_coarse<<<dim3((NE + 1023) / 1024, 3), 1024, 0, stream>>>(
      srcp[0], srcp[1], srcp[2], dstp[0], dstp[1], dstp[2], curB, staging);
  k_fine<<<dim3(NBKT, 3), 1024, 0, stream>>>(rowptr3, staging, srcord3);

  // one full GAT layer for metapath g -> bf16 ob
  auto gat = [&](int g, unsigned short* ob) {
    k_gemm_gat<<<dim3((NN + 127) / 128, NHD / 128), 256, 0, stream>>>(
        featb3 + (size_t)g * FEAT_SZ, wtb3 + (size_t)g * WTB_SZ, hb, alp[g], arp[g], el, er);
    k_aggf<<<NN * 64 / 256, 256, 0, stream>>>(rowptr3 + g * (NN + 1), srcord3 + (size_t)g * NE,
                                              el, er, hb, bp[g], ob);
  };

  gat(0, ob0);
  gat(2, ob2);

  // ---- semantic stage 1: rows<CC from ob0, rows>=CC from ob2 -> sound ----
  k_gemm_sem<<<(2 * CC + 127) / 128, 256, 0, stream>>>(ob0, ob2, w1tb2, sb1, sw2, scal);
  k_combine_s1<<<CC * NHD / 4 / 256, 256, 0, stream>>>(scal, ob0, ob2, sound);

  gat(1, ob1);

  // ---- semantic stage 2: rows<CC from sound, rows>=CC from ob1 -> combine+means ----
  k_gemm_sem<<<(2 * CC + 127) / 128, 256, 0, stream>>>(sound, ob1, w1tb2 + W1TB_SZ, ab1, aw2, scal + 2);
  k_comb2_means<<<NN * 64 / 256, 256, 0, stream>>>(scal + 2, sound, ob0, ob1, ob2,
                                                   outf, outm1, outm2, outm3);
}

// Round 13
// 456.008 us; speedup vs baseline: 1.2772x; 1.0092x over previous
//
#include <hip/hip_runtime.h>
#include <math.h>

#define NN 20000
#define NE 320000
#define CC 10000
#define KIN 768
#define NH 8
#define ND 64
#define NHD 512
#define NSA 128
#define NBKT 79                 // buckets of 256 nodes: 79*256 = 20224 >= NN

#define WTB_SZ (NHD * KIN)      // 393216 per graph
#define W1TB_SZ (NSA * NHD)     // 65536 per stage

typedef __attribute__((ext_vector_type(4))) float f32x4;
typedef __attribute__((ext_vector_type(8))) short s16x8;

__device__ __forceinline__ unsigned short f2bf(float f) {
  unsigned u = __float_as_uint(f);
  u += 0x7fffu + ((u >> 16) & 1u);
  return (unsigned short)(u >> 16);
}
__device__ __forceinline__ float bf2f(unsigned short s) {
  return __uint_as_float(((unsigned)s) << 16);
}
__device__ __forceinline__ float bflo(unsigned u) { return __uint_as_float(u << 16); }
__device__ __forceinline__ float bfhi(unsigned u) { return __uint_as_float(u & 0xffff0000u); }

__device__ __forceinline__ void gl_lds16(const void* g, void* l) {
  __builtin_amdgcn_global_load_lds(
      (const __attribute__((address_space(1))) unsigned int*)g,
      (__attribute__((address_space(3))) unsigned int*)l, 16, 0, 0);
}

// ---------------- prep: all weight transposes + zero deg3 + zero scal ----------------
__global__ void k_prep(const float* __restrict__ W0, const float* __restrict__ W1,
                       const float* __restrict__ W2, const float* __restrict__ sw1,
                       const float* __restrict__ aw1, unsigned short* __restrict__ wtb3,
                       unsigned short* __restrict__ w1tb2, int* __restrict__ deg3,
                       float* __restrict__ scal) {
  int i = blockIdx.x * 256 + threadIdx.x;
  if (i < 3 * WTB_SZ) {
    int g = i / WTB_SZ;
    int j = i - g * WTB_SZ;
    int n = j / KIN, k = j - n * KIN;
    const float* W = (g == 0) ? W0 : (g == 1) ? W1 : W2;
    wtb3[i] = f2bf(W[(size_t)k * NHD + n]);
    return;
  }
  i -= 3 * WTB_SZ;
  if (i < 2 * W1TB_SZ) {
    int p = i / W1TB_SZ;
    int j = i - p * W1TB_SZ;
    int n = j / NHD, k = j - n * NHD;
    const float* W = p ? aw1 : sw1;
    w1tb2[p * W1TB_SZ + n * NHD + k] = f2bf(W[(size_t)k * NSA + n]);
    return;
  }
  i -= 2 * W1TB_SZ;
  if (i < 3 * NN) { deg3[i] = 0; return; }
  i -= 3 * NN;
  if (i < 4) scal[i] = 0.f;
}

// ---------------- GAT GEMM: hb[M,512](bf16) = A[M,768](f32, cast inline) @ Wt^T ----------------
// A-staging: reg-staged f32->bf16 (2x float4 load, pack, ds_write_b128 to the SAME
// linear LDS slot global_load_lds used). B-staging: async gl_lds16 (bf16 weights).
// Fused epilogue: el[row*NH+h], er likewise.
__global__ __launch_bounds__(256, 2) void k_gemm_gat(const float* __restrict__ A,
                                                     const unsigned short* __restrict__ Bt,
                                                     unsigned short* __restrict__ outb,
                                                     const float* __restrict__ al,
                                                     const float* __restrict__ ar,
                                                     float* __restrict__ el,
                                                     float* __restrict__ er) {
  __shared__ unsigned short As[128 * 32];
  __shared__ unsigned short Bs[128 * 32];
  const int tid = threadIdx.x;
  const int wv = tid >> 6, lane = tid & 63;
  const int row0 = blockIdx.x * 128;
  const int col0 = blockIdx.y * 128;
  const int wr = (wv >> 1) * 64, wc = (wv & 1) * 64;
  const int ci = lane & 3, rsub = lane >> 2;

  f32x4 acc[4][4] = {};

  const int l15 = lane & 15;
  const int pc = (((lane >> 4) ^ ((l15 >> 1) & 3))) * 8;

  for (int k0 = 0; k0 < KIN; k0 += 32) {
#pragma unroll
    for (int i = 0; i < 2; i++) {
      int lrow = (wv * 2 + i) * 16 + rsub;
      int kc = (ci ^ ((lrow >> 1) & 3)) << 3;       // pre-swizzled chunk (same as before)
      int ga = row0 + lrow; if (ga > NN - 1) ga = NN - 1;
      const float* ap = A + (size_t)ga * KIN + k0 + kc;
      float4 f0 = ((const float4*)ap)[0];
      float4 f1 = ((const float4*)ap)[1];
      int gb = col0 + lrow;
      gl_lds16(Bt + (size_t)gb * KIN + k0 + kc, Bs + (wv * 2 + i) * 512);
      uint4 pk;
      pk.x = ((unsigned)f2bf(f0.y) << 16) | f2bf(f0.x);
      pk.y = ((unsigned)f2bf(f0.w) << 16) | f2bf(f0.z);
      pk.z = ((unsigned)f2bf(f1.y) << 16) | f2bf(f1.x);
      pk.w = ((unsigned)f2bf(f1.w) << 16) | f2bf(f1.z);
      *(uint4*)(As + (wv * 2 + i) * 512 + lane * 8) = pk;   // same slot gl_lds16 wrote
    }
    __syncthreads();
    s16x8 af[4], bf[4];
#pragma unroll
    for (int m = 0; m < 4; m++) {
      af[m] = *(const s16x8*)(As + (wr + m * 16 + l15) * 32 + pc);
      bf[m] = *(const s16x8*)(Bs + (wc + m * 16 + l15) * 32 + pc);
    }
#pragma unroll
    for (int m = 0; m < 4; m++)
#pragma unroll
      for (int n = 0; n < 4; n++)
        acc[m][n] = __builtin_amdgcn_mfma_f32_16x16x32_bf16(af[m], bf[n], acc[m][n], 0, 0, 0);
    __syncthreads();
  }

  const int cbase = col0 + wc + l15;
  const int rq = (lane >> 4) * 4;
  const int hd = (col0 + wc) >> 6;   // head owned by this wave
  float alc[4], arc[4];
#pragma unroll
  for (int n = 0; n < 4; n++) { alc[n] = al[cbase + n * 16]; arc[n] = ar[cbase + n * 16]; }

#pragma unroll
  for (int m = 0; m < 4; m++) {
#pragma unroll
    for (int r = 0; r < 4; r++) {
      int grow = row0 + wr + m * 16 + rq + r;
      float a = 0.f, b = 0.f;
#pragma unroll
      for (int n = 0; n < 4; n++) {
        float v = acc[m][n][r];
        a += v * alc[n];
        b += v * arc[n];
      }
      a += __shfl_xor(a, 1, 64); a += __shfl_xor(a, 2, 64);
      a += __shfl_xor(a, 4, 64); a += __shfl_xor(a, 8, 64);
      b += __shfl_xor(b, 1, 64); b += __shfl_xor(b, 2, 64);
      b += __shfl_xor(b, 4, 64); b += __shfl_xor(b, 8, 64);
      if (grow < NN) {
        unsigned short* dp = outb + (size_t)grow * NHD + cbase;
#pragma unroll
        for (int n = 0; n < 4; n++) dp[n * 16] = f2bf(acc[m][n][r]);
        if (l15 == 0) {
          el[(size_t)grow * NH + hd] = a;
          er[(size_t)grow * NH + hd] = b;
        }
      }
    }
  }
}

// ---------------- semantic GEMM with fused tanh*w2 row-reduce ----------------
// A rows: row<CC from A0[row], else A1[row-CC]. Accumulates scal[0]/scal[1].
__global__ __launch_bounds__(256, 2) void k_gemm_sem(const unsigned short* __restrict__ A0,
                                                     const unsigned short* __restrict__ A1,
                                                     const unsigned short* __restrict__ Bt,
                                                     const float* __restrict__ b1,
                                                     const float* __restrict__ w2,
                                                     float* __restrict__ scal) {
  __shared__ unsigned short As[128 * 32];
  __shared__ unsigned short Bs[128 * 32];
  __shared__ float rsum[2][128];
  __shared__ float pp[2][2];
  const int M = 2 * CC;
  const int tid = threadIdx.x;
  const int wv = tid >> 6, lane = tid & 63;
  const int row0 = blockIdx.x * 128;
  const int wr = (wv >> 1) * 64, wc = (wv & 1) * 64;
  const int ci = lane & 3, rsub = lane >> 2;

  f32x4 acc[4][4] = {};

  const int l15 = lane & 15;
  const int pc = (((lane >> 4) ^ ((l15 >> 1) & 3))) * 8;

  for (int k0 = 0; k0 < NHD; k0 += 32) {
#pragma unroll
    for (int i = 0; i < 2; i++) {
      int lrow = (wv * 2 + i) * 16 + rsub;
      int kc = (ci ^ ((lrow >> 1) & 3)) << 3;
      int ga = row0 + lrow; if (ga > M - 1) ga = M - 1;
      const unsigned short* Ap = (ga < CC) ? A0 + (size_t)ga * NHD
                                           : A1 + (size_t)(ga - CC) * NHD;
      gl_lds16(Ap + k0 + kc, As + (wv * 2 + i) * 512);
      int gb = lrow;  // col0 = 0, Nb = 128
      gl_lds16(Bt + (size_t)gb * NHD + k0 + kc, Bs + (wv * 2 + i) * 512);
    }
    __syncthreads();
    s16x8 af[4], bf[4];
#pragma unroll
    for (int m = 0; m < 4; m++) {
      af[m] = *(const s16x8*)(As + (wr + m * 16 + l15) * 32 + pc);
      bf[m] = *(const s16x8*)(Bs + (wc + m * 16 + l15) * 32 + pc);
    }
#pragma unroll
    for (int m = 0; m < 4; m++)
#pragma unroll
      for (int n = 0; n < 4; n++)
        acc[m][n] = __builtin_amdgcn_mfma_f32_16x16x32_bf16(af[m], bf[n], acc[m][n], 0, 0, 0);
    __syncthreads();
  }

  if (tid < 128) { rsum[0][tid] = 0.f; rsum[1][tid] = 0.f; }
  __syncthreads();
  const int cb = wc + l15;
  const int rq = (lane >> 4) * 4;
  float b1c[4], w2c[4];
#pragma unroll
  for (int n = 0; n < 4; n++) { b1c[n] = b1[cb + n * 16]; w2c[n] = w2[cb + n * 16]; }
#pragma unroll
  for (int m = 0; m < 4; m++) {
#pragma unroll
    for (int r = 0; r < 4; r++) {
      int rl = wr + m * 16 + rq + r;
      float s = 0.f;
#pragma unroll
      for (int n = 0; n < 4; n++) s += tanhf(acc[m][n][r] + b1c[n]) * w2c[n];
      s += __shfl_xor(s, 1, 64); s += __shfl_xor(s, 2, 64);
      s += __shfl_xor(s, 4, 64); s += __shfl_xor(s, 8, 64);
      if (l15 == 0 && row0 + rl < M) rsum[wv & 1][rl] = s;
    }
  }
  __syncthreads();
  if (tid < 128) {
    int grow = row0 + tid;
    float v = rsum[0][tid] + rsum[1][tid];
    float vA = (grow < CC) ? v : 0.f;
    float vB = (grow >= CC && grow < M) ? v : 0.f;
#pragma unroll
    for (int off = 32; off > 0; off >>= 1) {
      vA += __shfl_xor(vA, off, 64);
      vB += __shfl_xor(vB, off, 64);
    }
    if ((tid & 63) == 0) { pp[tid >> 6][0] = vA; pp[tid >> 6][1] = vB; }
  }
  __syncthreads();
  if (tid == 0) {
    atomicAdd(scal + 0, pp[0][0] + pp[1][0]);
    atomicAdd(scal + 1, pp[0][1] + pp[1][1]);
  }
}

// ---------------- batched CSR build (3 graphs), bucket-staged scatter ----------------
__global__ void k_hist3(const int* __restrict__ d0, const int* __restrict__ d1,
                        const int* __restrict__ d2, int* __restrict__ deg3) {
  int e = blockIdx.x * 256 + threadIdx.x;
  int g = blockIdx.y;
  const int* dst = (g == 0) ? d0 : (g == 1) ? d1 : d2;
  atomicAdd(deg3 + g * NN + dst[e], 1);
}

__global__ __launch_bounds__(1024) void k_scan3(const int* __restrict__ deg3,
                                                int* __restrict__ rowptr3,
                                                int* __restrict__ curB) {
  __shared__ int part[1024];
  const int g = blockIdx.x;
  const int* deg = deg3 + g * NN;
  int* rowptr = rowptr3 + g * (NN + 1);
  int tid = threadIdx.x;
  const int CH = 20;
  int base = tid * CH;
  int s = 0;
  for (int i = 0; i < CH; i++) { int idx = base + i; if (idx < NN) s += deg[idx]; }
  part[tid] = s;
  __syncthreads();
  for (int off = 1; off < 1024; off <<= 1) {
    int u = (tid >= off) ? part[tid - off] : 0;
    int v = part[tid];
    __syncthreads();
    part[tid] = u + v;
    __syncthreads();
  }
  int run = (tid == 0) ? 0 : part[tid - 1];
  for (int i = 0; i < CH; i++) {
    int idx = base + i;
    if (idx < NN) {
      rowptr[idx] = run;
      if ((idx & 255) == 0) curB[g * (NBKT + 1) + (idx >> 8)] = run;
      run += deg[idx];
    }
  }
  if (tid == 1023) rowptr[NN] = part[1023];
}

__global__ __launch_bounds__(1024) void k_coarse(const int* __restrict__ s0,
                                                 const int* __restrict__ s1,
                                                 const int* __restrict__ s2,
                                                 const int* __restrict__ d0,
                                                 const int* __restrict__ d1,
                                                 const int* __restrict__ d2,
                                                 int* __restrict__ curB,
                                                 unsigned* __restrict__ staging) {
  __shared__ int bcnt[NBKT];
  __shared__ int bbase[NBKT];
  int g = blockIdx.y;
  const int* src = (g == 0) ? s0 : (g == 1) ? s1 : s2;
  const int* dst = (g == 0) ? d0 : (g == 1) ? d1 : d2;
  int tid = threadIdx.x;
  if (tid < NBKT) bcnt[tid] = 0;
  __syncthreads();
  int e = blockIdx.x * 1024 + tid;
  bool val = e < NE;
  int b = 0, r = 0, sv = 0, dv = 0;
  if (val) {
    dv = dst[e]; sv = src[e];
    b = dv >> 8;
    r = atomicAdd(&bcnt[b], 1);
  }
  __syncthreads();
  if (tid < NBKT && bcnt[tid] > 0) bbase[tid] = atomicAdd(&curB[g * (NBKT + 1) + tid], bcnt[tid]);
  __syncthreads();
  if (val) staging[(size_t)g * NE + bbase[b] + r] = ((unsigned)sv << 8) | (unsigned)(dv & 255);
}

__global__ __launch_bounds__(1024) void k_fine(const int* __restrict__ rowptr3,
                                               const unsigned* __restrict__ staging,
                                               unsigned short* __restrict__ srcord3) {
  __shared__ int cur[256];
  int g = blockIdx.y, b = blockIdx.x;
  const int* rowptr = rowptr3 + g * (NN + 1);
  int n0 = b << 8;
  int tid = threadIdx.x;
  if (tid < 256) {
    int node = n0 + tid;
    cur[tid] = (node < NN) ? rowptr[node] : 0;
  }
  __syncthreads();
  int nend = n0 + 256; if (nend > NN) nend = NN;
  int start = rowptr[n0];
  int endp = rowptr[nend];
  for (int i = start + tid; i < endp; i += 1024) {
    unsigned u = staging[(size_t)g * NE + i];
    int nl = u & 255;
    int pos = atomicAdd(&cur[nl], 1);
    srcord3[(size_t)g * NE + pos] = (unsigned short)(u >> 8);
  }
}

// ---------------- FUSED softmax + gather aggregation + bias + elu (bf16 out) ----------------
// wave per node; lane = 16B slice of the 512-wide row, head = lane>>3.
__global__ __launch_bounds__(256) void k_aggf(const int* __restrict__ rowptr,
                                              const unsigned short* __restrict__ srcord,
                                              const float* __restrict__ el,
                                              const float* __restrict__ er,
                                              const unsigned short* __restrict__ hb,
                                              const float* __restrict__ bias,
                                              unsigned short* __restrict__ ob) {
  __shared__ float aS[4][64 * 8];
  __shared__ int sS[4][64];
  int wv = threadIdx.x >> 6;
  int t = (blockIdx.x * 256 + threadIdx.x) >> 6;
  int lane = threadIdx.x & 63;
  int h = lane >> 3;
  int beg = rowptr[t], end = rowptr[t + 1];

  float4 er0 = ((const float4*)(er + (size_t)t * NH))[0];
  float4 er1 = ((const float4*)(er + (size_t)t * NH))[1];
  float erow[8] = {er0.x, er0.y, er0.z, er0.w, er1.x, er1.y, er1.z, er1.w};

  float acc[8] = {0.f, 0.f, 0.f, 0.f, 0.f, 0.f, 0.f, 0.f};
  float den = 0.f;

  for (int cbeg = beg; cbeg < end; cbeg += 64) {
    int cnt = end - cbeg; if (cnt > 64) cnt = 64;
    bool valid = lane < cnt;
    int pidx = cbeg + lane; if (pidx > end - 1) pidx = end - 1;
    int s = srcord[pidx];
    if (valid) {
      sS[wv][lane] = s;
      float4 a0 = ((const float4*)(el + (size_t)s * NH))[0];
      float4 a1 = ((const float4*)(el + (size_t)s * NH))[1];
      float v[8] = {a0.x + erow[0], a0.y + erow[1], a0.z + erow[2], a0.w + erow[3],
                    a1.x + erow[4], a1.y + erow[5], a1.z + erow[6], a1.w + erow[7]};
#pragma unroll
      for (int k = 0; k < 8; k++) {
        float x = v[k];
        x = x >= 0.f ? x : 0.2f * x;
        aS[wv][lane * 8 + k] = __expf(x);
      }
    }
    const unsigned short* hbl = hb + lane * 8;
    int q = 0;
    for (; q + 3 < cnt; q += 4) {
      int s0 = sS[wv][q], s1 = sS[wv][q + 1], s2 = sS[wv][q + 2], s3 = sS[wv][q + 3];
      float w0 = aS[wv][q * 8 + h];
      float w1 = aS[wv][(q + 1) * 8 + h];
      float w2 = aS[wv][(q + 2) * 8 + h];
      float w3 = aS[wv][(q + 3) * 8 + h];
      uint4 v0 = *(const uint4*)(hbl + (size_t)s0 * NHD);
      uint4 v1 = *(const uint4*)(hbl + (size_t)s1 * NHD);
      uint4 v2 = *(const uint4*)(hbl + (size_t)s2 * NHD);
      uint4 v3 = *(const uint4*)(hbl + (size_t)s3 * NHD);
      den += (w0 + w1) + (w2 + w3);
      acc[0] += w0 * bflo(v0.x); acc[1] += w0 * bfhi(v0.x);
      acc[2] += w0 * bflo(v0.y); acc[3] += w0 * bfhi(v0.y);
      acc[4] += w0 * bflo(v0.z); acc[5] += w0 * bfhi(v0.z);
      acc[6] += w0 * bflo(v0.w); acc[7] += w0 * bfhi(v0.w);
      acc[0] += w1 * bflo(v1.x); acc[1] += w1 * bfhi(v1.x);
      acc[2] += w1 * bflo(v1.y); acc[3] += w1 * bfhi(v1.y);
      acc[4] += w1 * bflo(v1.z); acc[5] += w1 * bfhi(v1.z);
      acc[6] += w1 * bflo(v1.w); acc[7] += w1 * bfhi(v1.w);
      acc[0] += w2 * bflo(v2.x); acc[1] += w2 * bfhi(v2.x);
      acc[2] += w2 * bflo(v2.y); acc[3] += w2 * bfhi(v2.y);
      acc[4] += w2 * bflo(v2.z); acc[5] += w2 * bfhi(v2.z);
      acc[6] += w2 * bflo(v2.w); acc[7] += w2 * bfhi(v2.w);
      acc[0] += w3 * bflo(v3.x); acc[1] += w3 * bfhi(v3.x);
      acc[2] += w3 * bflo(v3.y); acc[3] += w3 * bfhi(v3.y);
      acc[4] += w3 * bflo(v3.z); acc[5] += w3 * bfhi(v3.z);
      acc[6] += w3 * bflo(v3.w); acc[7] += w3 * bfhi(v3.w);
    }
    for (; q < cnt; q++) {
      int s0 = sS[wv][q];
      float w0 = aS[wv][q * 8 + h];
      uint4 v0 = *(const uint4*)(hbl + (size_t)s0 * NHD);
      den += w0;
      acc[0] += w0 * bflo(v0.x); acc[1] += w0 * bfhi(v0.x);
      acc[2] += w0 * bflo(v0.y); acc[3] += w0 * bfhi(v0.y);
      acc[4] += w0 * bflo(v0.z); acc[5] += w0 * bfhi(v0.z);
      acc[6] += w0 * bflo(v0.w); acc[7] += w0 * bfhi(v0.w);
    }
  }

  float dn = 1.f / fmaxf(den, 1e-9f);
  float4 b0 = ((const float4*)(bias + lane * 8))[0];
  float4 b1 = ((const float4*)(bias + lane * 8))[1];
  float r[8];
  r[0] = acc[0] * dn + b0.x; r[1] = acc[1] * dn + b0.y;
  r[2] = acc[2] * dn + b0.z; r[3] = acc[3] * dn + b0.w;
  r[4] = acc[4] * dn + b1.x; r[5] = acc[5] * dn + b1.y;
  r[6] = acc[6] * dn + b1.z; r[7] = acc[7] * dn + b1.w;
#pragma unroll
  for (int j = 0; j < 8; j++) r[j] = r[j] > 0.f ? r[j] : expm1f(r[j]);
  uint4 z;
  z.x = ((unsigned)f2bf(r[1]) << 16) | f2bf(r[0]);
  z.y = ((unsigned)f2bf(r[3]) << 16) | f2bf(r[2]);
  z.z = ((unsigned)f2bf(r[5]) << 16) | f2bf(r[4]);
  z.w = ((unsigned)f2bf(r[7]) << 16) | f2bf(r[6]);
  *(uint4*)(ob + (size_t)t * NHD + lane * 8) = z;
}

// stage 1: sound(bf16) = beta0*zA(bf16) + beta1*zB(bf16)
__global__ void k_combine_s1(const float* __restrict__ scal,
                             const unsigned short* __restrict__ zA,
                             const unsigned short* __restrict__ zB,
                             unsigned short* __restrict__ outb) {
  int i = blockIdx.x * 256 + threadIdx.x;   // grid exact CC*NHD/4
  float w0 = scal[0] * (1.f / CC), w1v = scal[1] * (1.f / CC);
  float mx = fmaxf(w0, w1v);
  float e0 = expf(w0 - mx), e1 = expf(w1v - mx);
  float inv = 1.f / (e0 + e1);
  float b0 = e0 * inv, b1v = e1 * inv;
  ushort4 a = ((const ushort4*)zA)[i];
  ushort4 b = ((const ushort4*)zB)[i];
  ushort4 z;
  z.x = f2bf(b0 * bf2f(a.x) + b1v * bf2f(b.x));
  z.y = f2bf(b0 * bf2f(a.y) + b1v * bf2f(b.y));
  z.z = f2bf(b0 * bf2f(a.z) + b1v * bf2f(b.z));
  z.w = f2bf(b0 * bf2f(a.w) + b1v * bf2f(b.w));
  ((ushort4*)outb)[i] = z;
}

// ---------------- fused stage-2 combine + final head-means (bf16 inputs) ----------------
__global__ void k_comb2_means(const float* __restrict__ scal,
                              const unsigned short* __restrict__ zsound,
                              const unsigned short* __restrict__ ob0,
                              const unsigned short* __restrict__ ob1,
                              const unsigned short* __restrict__ ob2,
                              float* __restrict__ outf,
                              float* __restrict__ m1, float* __restrict__ m2,
                              float* __restrict__ m3) {
  int idx = blockIdx.x * 256 + threadIdx.x;   // grid exact NN*64
  int n = idx >> 6, d = idx & 63;
  if (n < CC) {
    float w0 = scal[0] * (1.f / CC), w1v = scal[1] * (1.f / CC);
    float mx = fmaxf(w0, w1v);
    float e0 = expf(w0 - mx), e1 = expf(w1v - mx);
    float inv = 1.f / (e0 + e1);
    float b0 = e0 * inv, b1v = e1 * inv;
    const unsigned short* zs = zsound + (size_t)n * NHD + d;
    const unsigned short* p1 = ob1 + (size_t)n * NHD + d;
    float* po = outf + (size_t)n * NHD + d;
    float v = 0.f;
#pragma unroll
    for (int h = 0; h < 8; h++) {
      float r = b0 * bf2f(zs[h * 64]) + b1v * bf2f(p1[h * 64]);
      po[h * 64] = r;
      v += r;
    }
    v *= 0.125f;
    m1[idx] = v; m2[idx] = v; m3[idx] = v;
  } else {
    const unsigned short* p0 = ob0 + (size_t)n * NHD + d;
    const unsigned short* p1 = ob1 + (size_t)n * NHD + d;
    const unsigned short* p2 = ob2 + (size_t)n * NHD + d;
    float v0 = 0.f, v1 = 0.f, v2 = 0.f;
#pragma unroll
    for (int h = 0; h < 8; h++) {
      v0 += bf2f(p0[h * 64]); v1 += bf2f(p1[h * 64]); v2 += bf2f(p2[h * 64]);
    }
    m1[idx] = v0 * 0.125f; m2[idx] = v1 * 0.125f; m3[idx] = v2 * 0.125f;
  }
}

extern "C" void kernel_launch(void* const* d_in, const int* in_sizes, int n_in,
                              void* d_out, int out_size, void* d_ws, size_t ws_size,
                              hipStream_t stream) {
  (void)in_sizes; (void)n_in; (void)out_size; (void)ws_size;

  const float* feat[3]; const int* srcp[3]; const int* dstp[3];
  const float* Wp[3]; const float* alp[3]; const float* arp[3]; const float* bp[3];
  for (int g = 0; g < 3; g++) {
    const int base = g * 8;  // dict order: feat,src,dst,char,W,al,ar,b
    feat[g] = (const float*)d_in[base + 0];
    srcp[g] = (const int*)d_in[base + 1];
    dstp[g] = (const int*)d_in[base + 2];
    Wp[g]   = (const float*)d_in[base + 4];
    alp[g]  = (const float*)d_in[base + 5];
    arp[g]  = (const float*)d_in[base + 6];
    bp[g]   = (const float*)d_in[base + 7];
  }
  const float* sw1 = (const float*)d_in[24];
  const float* sb1 = (const float*)d_in[25];
  const float* sw2 = (const float*)d_in[26];
  const float* aw1 = (const float*)d_in[27];
  const float* ab1 = (const float*)d_in[28];
  const float* aw2 = (const float*)d_in[29];

  char* wsp = (char*)d_ws;
  auto alloc = [&](size_t bytes) {
    char* p = wsp;
    wsp += (bytes + 255) & ~(size_t)255;
    return p;
  };
  // total ~103 MB
  unsigned short* ob0 = (unsigned short*)alloc((size_t)NN * NHD * 2);   // 20.5 MB
  unsigned short* ob1 = (unsigned short*)alloc((size_t)NN * NHD * 2);   // 20.5 MB
  unsigned short* ob2 = (unsigned short*)alloc((size_t)NN * NHD * 2);   // 20.5 MB
  unsigned short* hb = (unsigned short*)alloc((size_t)NN * NHD * 2);    // 20.5 MB
  unsigned short* wtb3 = (unsigned short*)alloc((size_t)3 * WTB_SZ * 2);
  unsigned short* w1tb2 = (unsigned short*)alloc((size_t)2 * W1TB_SZ * 2);
  unsigned short* sound = (unsigned short*)alloc((size_t)CC * NHD * 2); // 10.2 MB
  float* el = (float*)alloc((size_t)NN * NH * 4);
  float* er = (float*)alloc((size_t)NN * NH * 4);
  float* scal = (float*)alloc(256);
  int* deg3 = (int*)alloc((size_t)3 * NN * 4);
  int* rowptr3 = (int*)alloc((size_t)3 * (NN + 1) * 4 + 64);
  int* curB = (int*)alloc((size_t)3 * (NBKT + 1) * 4);
  unsigned* staging = (unsigned*)alloc((size_t)3 * NE * 4);
  unsigned short* srcord3 = (unsigned short*)alloc((size_t)3 * NE * 2);

  float* outf = (float*)d_out;
  float* outm1 = outf + (size_t)CC * NHD;
  float* outm2 = outm1 + (size_t)NN * ND;
  float* outm3 = outm2 + (size_t)NN * ND;

  // ---- prep: weight transposes + zero deg3/scal; bucket-staged CSR build ----
  const int PREP_T = 3 * WTB_SZ + 2 * W1TB_SZ + 3 * NN + 4;
  k_prep<<<(PREP_T + 255) / 256, 256, 0, stream>>>(Wp[0], Wp[1], Wp[2], sw1, aw1,
                                                   wtb3, w1tb2, deg3, scal);
  k_hist3<<<dim3(NE / 256, 3), 256, 0, stream>>>(dstp[0], dstp[1], dstp[2], deg3);
  k_scan3<<<3, 1024, 0, stream>>>(deg3, rowptr3, curB);
  k_coarse<<<dim3((NE + 1023) / 1024, 3), 1024, 0, stream>>>(
      srcp[0], srcp[1], srcp[2], dstp[0], dstp[1], dstp[2], curB, staging);
  k_fine<<<dim3(NBKT, 3), 1024, 0, stream>>>(rowptr3, staging, srcord3);

  // one full GAT layer for metapath g -> bf16 ob (feat read f32, cast inline in GEMM)
  auto gat = [&](int g, unsigned short* ob) {
    k_gemm_gat<<<dim3((NN + 127) / 128, NHD / 128), 256, 0, stream>>>(
        feat[g], wtb3 + (size_t)g * WTB_SZ, hb, alp[g], arp[g], el, er);
    k_aggf<<<NN * 64 / 256, 256, 0, stream>>>(rowptr3 + g * (NN + 1), srcord3 + (size_t)g * NE,
                                              el, er, hb, bp[g], ob);
  };

  gat(0, ob0);
  gat(2, ob2);

  // ---- semantic stage 1: rows<CC from ob0, rows>=CC from ob2 -> sound ----
  k_gemm_sem<<<(2 * CC + 127) / 128, 256, 0, stream>>>(ob0, ob2, w1tb2, sb1, sw2, scal);
  k_combine_s1<<<CC * NHD / 4 / 256, 256, 0, stream>>>(scal, ob0, ob2, sound);

  gat(1, ob1);

  // ---- semantic stage 2: rows<CC from sound, rows>=CC from ob1 -> combine+means ----
  k_gemm_sem<<<(2 * CC + 127) / 128, 256, 0, stream>>>(sound, ob1, w1tb2 + W1TB_SZ, ab1, aw2, scal + 2);
  k_comb2_means<<<NN * 64 / 256, 256, 0, stream>>>(scal + 2, sound, ob0, ob1, ob2,
                                                   outf, outm1, outm2, outm3);
}

// Round 14
// 450.968 us; speedup vs baseline: 1.2915x; 1.0112x over previous
//
#include <hip/hip_runtime.h>
#include <math.h>

#define NN 20000
#define NE 320000
#define CC 10000
#define KIN 768
#define NH 8
#define ND 64
#define NHD 512
#define NSA 128
#define NBKT 79                 // buckets of 256 nodes: 79*256 = 20224 >= NN

#define WTB_SZ (NHD * KIN)      // 393216 per graph
#define W1TB_SZ (NSA * NHD)     // 65536 per stage

typedef __attribute__((ext_vector_type(4))) float f32x4;
typedef __attribute__((ext_vector_type(8))) short s16x8;

__device__ __forceinline__ unsigned short f2bf(float f) {
  unsigned u = __float_as_uint(f);
  u += 0x7fffu + ((u >> 16) & 1u);
  return (unsigned short)(u >> 16);
}
__device__ __forceinline__ float bf2f(unsigned short s) {
  return __uint_as_float(((unsigned)s) << 16);
}
__device__ __forceinline__ float bflo(unsigned u) { return __uint_as_float(u << 16); }
__device__ __forceinline__ float bfhi(unsigned u) { return __uint_as_float(u & 0xffff0000u); }

__device__ __forceinline__ void gl_lds16(const void* g, void* l) {
  __builtin_amdgcn_global_load_lds(
      (const __attribute__((address_space(1))) unsigned int*)g,
      (__attribute__((address_space(3))) unsigned int*)l, 16, 0, 0);
}

// ---------------- prep: all weight transposes + zero deg3 + zero scal ----------------
__global__ void k_prep(const float* __restrict__ W0, const float* __restrict__ W1,
                       const float* __restrict__ W2, const float* __restrict__ sw1,
                       const float* __restrict__ aw1, unsigned short* __restrict__ wtb3,
                       unsigned short* __restrict__ w1tb2, int* __restrict__ deg3,
                       float* __restrict__ scal) {
  int i = blockIdx.x * 256 + threadIdx.x;
  if (i < 3 * WTB_SZ) {
    int g = i / WTB_SZ;
    int j = i - g * WTB_SZ;
    int n = j / KIN, k = j - n * KIN;
    const float* W = (g == 0) ? W0 : (g == 1) ? W1 : W2;
    wtb3[i] = f2bf(W[(size_t)k * NHD + n]);
    return;
  }
  i -= 3 * WTB_SZ;
  if (i < 2 * W1TB_SZ) {
    int p = i / W1TB_SZ;
    int j = i - p * W1TB_SZ;
    int n = j / NHD, k = j - n * NHD;
    const float* W = p ? aw1 : sw1;
    w1tb2[p * W1TB_SZ + n * NHD + k] = f2bf(W[(size_t)k * NSA + n]);
    return;
  }
  i -= 2 * W1TB_SZ;
  if (i < 3 * NN) { deg3[i] = 0; return; }
  i -= 3 * NN;
  if (i < 4) scal[i] = 0.f;
}

// ---------------- GAT GEMM: hb[M,512](bf16) = A[M,768](f32, cast inline) @ Wt^T ----------------
// Grid is linear (640 blocks); decode bid so XCD x (= bid%8, measured round-robin)
// executes the 4 column-tiles of each of its row-blocks back-to-back -> the 384KB
// f32 A-panel stays hot in that XCD's 4MB L2 (3 of 4 A reads become L2 hits).
// A-staging: reg-staged f32->bf16; B-staging: async gl_lds16.
// Fused epilogue: el[row*NH+h], er likewise.
__global__ __launch_bounds__(256, 2) void k_gemm_gat(const float* __restrict__ A,
                                                     const unsigned short* __restrict__ Bt,
                                                     unsigned short* __restrict__ outb,
                                                     const float* __restrict__ al,
                                                     const float* __restrict__ ar,
                                                     float* __restrict__ el,
                                                     float* __restrict__ er) {
  __shared__ unsigned short As[128 * 32];
  __shared__ unsigned short Bs[128 * 32];
  const int bid = blockIdx.x;
  const int xcd = bid & 7, t = bid >> 3;
  const int rowblk = (t >> 2) * 8 + xcd;
  if (rowblk * 128 >= NN) return;
  const int row0 = rowblk * 128;
  const int col0 = (t & 3) * 128;
  const int tid = threadIdx.x;
  const int wv = tid >> 6, lane = tid & 63;
  const int wr = (wv >> 1) * 64, wc = (wv & 1) * 64;
  const int ci = lane & 3, rsub = lane >> 2;

  f32x4 acc[4][4] = {};

  const int l15 = lane & 15;
  const int pc = (((lane >> 4) ^ ((l15 >> 1) & 3))) * 8;

  for (int k0 = 0; k0 < KIN; k0 += 32) {
#pragma unroll
    for (int i = 0; i < 2; i++) {
      int lrow = (wv * 2 + i) * 16 + rsub;
      int kc = (ci ^ ((lrow >> 1) & 3)) << 3;       // pre-swizzled chunk
      int ga = row0 + lrow; if (ga > NN - 1) ga = NN - 1;
      const float* ap = A + (size_t)ga * KIN + k0 + kc;
      float4 f0 = ((const float4*)ap)[0];
      float4 f1 = ((const float4*)ap)[1];
      int gb = col0 + lrow;
      gl_lds16(Bt + (size_t)gb * KIN + k0 + kc, Bs + (wv * 2 + i) * 512);
      uint4 pk;
      pk.x = ((unsigned)f2bf(f0.y) << 16) | f2bf(f0.x);
      pk.y = ((unsigned)f2bf(f0.w) << 16) | f2bf(f0.z);
      pk.z = ((unsigned)f2bf(f1.y) << 16) | f2bf(f1.x);
      pk.w = ((unsigned)f2bf(f1.w) << 16) | f2bf(f1.z);
      *(uint4*)(As + (wv * 2 + i) * 512 + lane * 8) = pk;   // same slot gl_lds16 wrote
    }
    __syncthreads();
    s16x8 af[4], bf[4];
#pragma unroll
    for (int m = 0; m < 4; m++) {
      af[m] = *(const s16x8*)(As + (wr + m * 16 + l15) * 32 + pc);
      bf[m] = *(const s16x8*)(Bs + (wc + m * 16 + l15) * 32 + pc);
    }
#pragma unroll
    for (int m = 0; m < 4; m++)
#pragma unroll
      for (int n = 0; n < 4; n++)
        acc[m][n] = __builtin_amdgcn_mfma_f32_16x16x32_bf16(af[m], bf[n], acc[m][n], 0, 0, 0);
    __syncthreads();
  }

  const int cbase = col0 + wc + l15;
  const int rq = (lane >> 4) * 4;
  const int hd = (col0 + wc) >> 6;   // head owned by this wave
  float alc[4], arc[4];
#pragma unroll
  for (int n = 0; n < 4; n++) { alc[n] = al[cbase + n * 16]; arc[n] = ar[cbase + n * 16]; }

#pragma unroll
  for (int m = 0; m < 4; m++) {
#pragma unroll
    for (int r = 0; r < 4; r++) {
      int grow = row0 + wr + m * 16 + rq + r;
      float a = 0.f, b = 0.f;
#pragma unroll
      for (int n = 0; n < 4; n++) {
        float v = acc[m][n][r];
        a += v * alc[n];
        b += v * arc[n];
      }
      a += __shfl_xor(a, 1, 64); a += __shfl_xor(a, 2, 64);
      a += __shfl_xor(a, 4, 64); a += __shfl_xor(a, 8, 64);
      b += __shfl_xor(b, 1, 64); b += __shfl_xor(b, 2, 64);
      b += __shfl_xor(b, 4, 64); b += __shfl_xor(b, 8, 64);
      if (grow < NN) {
        unsigned short* dp = outb + (size_t)grow * NHD + cbase;
#pragma unroll
        for (int n = 0; n < 4; n++) dp[n * 16] = f2bf(acc[m][n][r]);
        if (l15 == 0) {
          el[(size_t)grow * NH + hd] = a;
          er[(size_t)grow * NH + hd] = b;
        }
      }
    }
  }
}

// ---------------- semantic GEMM with fused tanh*w2 row-reduce ----------------
// A rows: row<CC from A0[row], else A1[row-CC]. Accumulates scal[0]/scal[1].
__global__ __launch_bounds__(256, 2) void k_gemm_sem(const unsigned short* __restrict__ A0,
                                                     const unsigned short* __restrict__ A1,
                                                     const unsigned short* __restrict__ Bt,
                                                     const float* __restrict__ b1,
                                                     const float* __restrict__ w2,
                                                     float* __restrict__ scal) {
  __shared__ unsigned short As[128 * 32];
  __shared__ unsigned short Bs[128 * 32];
  __shared__ float rsum[2][128];
  __shared__ float pp[2][2];
  const int M = 2 * CC;
  const int tid = threadIdx.x;
  const int wv = tid >> 6, lane = tid & 63;
  const int row0 = blockIdx.x * 128;
  const int wr = (wv >> 1) * 64, wc = (wv & 1) * 64;
  const int ci = lane & 3, rsub = lane >> 2;

  f32x4 acc[4][4] = {};

  const int l15 = lane & 15;
  const int pc = (((lane >> 4) ^ ((l15 >> 1) & 3))) * 8;

  for (int k0 = 0; k0 < NHD; k0 += 32) {
#pragma unroll
    for (int i = 0; i < 2; i++) {
      int lrow = (wv * 2 + i) * 16 + rsub;
      int kc = (ci ^ ((lrow >> 1) & 3)) << 3;
      int ga = row0 + lrow; if (ga > M - 1) ga = M - 1;
      const unsigned short* Ap = (ga < CC) ? A0 + (size_t)ga * NHD
                                           : A1 + (size_t)(ga - CC) * NHD;
      gl_lds16(Ap + k0 + kc, As + (wv * 2 + i) * 512);
      int gb = lrow;  // col0 = 0, Nb = 128
      gl_lds16(Bt + (size_t)gb * NHD + k0 + kc, Bs + (wv * 2 + i) * 512);
    }
    __syncthreads();
    s16x8 af[4], bf[4];
#pragma unroll
    for (int m = 0; m < 4; m++) {
      af[m] = *(const s16x8*)(As + (wr + m * 16 + l15) * 32 + pc);
      bf[m] = *(const s16x8*)(Bs + (wc + m * 16 + l15) * 32 + pc);
    }
#pragma unroll
    for (int m = 0; m < 4; m++)
#pragma unroll
      for (int n = 0; n < 4; n++)
        acc[m][n] = __builtin_amdgcn_mfma_f32_16x16x32_bf16(af[m], bf[n], acc[m][n], 0, 0, 0);
    __syncthreads();
  }

  if (tid < 128) { rsum[0][tid] = 0.f; rsum[1][tid] = 0.f; }
  __syncthreads();
  const int cb = wc + l15;
  const int rq = (lane >> 4) * 4;
  float b1c[4], w2c[4];
#pragma unroll
  for (int n = 0; n < 4; n++) { b1c[n] = b1[cb + n * 16]; w2c[n] = w2[cb + n * 16]; }
#pragma unroll
  for (int m = 0; m < 4; m++) {
#pragma unroll
    for (int r = 0; r < 4; r++) {
      int rl = wr + m * 16 + rq + r;
      float s = 0.f;
#pragma unroll
      for (int n = 0; n < 4; n++) s += tanhf(acc[m][n][r] + b1c[n]) * w2c[n];
      s += __shfl_xor(s, 1, 64); s += __shfl_xor(s, 2, 64);
      s += __shfl_xor(s, 4, 64); s += __shfl_xor(s, 8, 64);
      if (l15 == 0 && row0 + rl < M) rsum[wv & 1][rl] = s;
    }
  }
  __syncthreads();
  if (tid < 128) {
    int grow = row0 + tid;
    float v = rsum[0][tid] + rsum[1][tid];
    float vA = (grow < CC) ? v : 0.f;
    float vB = (grow >= CC && grow < M) ? v : 0.f;
#pragma unroll
    for (int off = 32; off > 0; off >>= 1) {
      vA += __shfl_xor(vA, off, 64);
      vB += __shfl_xor(vB, off, 64);
    }
    if ((tid & 63) == 0) { pp[tid >> 6][0] = vA; pp[tid >> 6][1] = vB; }
  }
  __syncthreads();
  if (tid == 0) {
    atomicAdd(scal + 0, pp[0][0] + pp[1][0]);
    atomicAdd(scal + 1, pp[0][1] + pp[1][1]);
  }
}

// ---------------- batched CSR build (3 graphs), bucket-staged scatter ----------------
__global__ void k_hist3(const int* __restrict__ d0, const int* __restrict__ d1,
                        const int* __restrict__ d2, int* __restrict__ deg3) {
  int e = blockIdx.x * 256 + threadIdx.x;
  int g = blockIdx.y;
  const int* dst = (g == 0) ? d0 : (g == 1) ? d1 : d2;
  atomicAdd(deg3 + g * NN + dst[e], 1);
}

__global__ __launch_bounds__(1024) void k_scan3(const int* __restrict__ deg3,
                                                int* __restrict__ rowptr3,
                                                int* __restrict__ curB) {
  __shared__ int part[1024];
  const int g = blockIdx.x;
  const int* deg = deg3 + g * NN;
  int* rowptr = rowptr3 + g * (NN + 1);
  int tid = threadIdx.x;
  const int CH = 20;
  int base = tid * CH;
  int s = 0;
  for (int i = 0; i < CH; i++) { int idx = base + i; if (idx < NN) s += deg[idx]; }
  part[tid] = s;
  __syncthreads();
  for (int off = 1; off < 1024; off <<= 1) {
    int u = (tid >= off) ? part[tid - off] : 0;
    int v = part[tid];
    __syncthreads();
    part[tid] = u + v;
    __syncthreads();
  }
  int run = (tid == 0) ? 0 : part[tid - 1];
  for (int i = 0; i < CH; i++) {
    int idx = base + i;
    if (idx < NN) {
      rowptr[idx] = run;
      if ((idx & 255) == 0) curB[g * (NBKT + 1) + (idx >> 8)] = run;
      run += deg[idx];
    }
  }
  if (tid == 1023) rowptr[NN] = part[1023];
}

__global__ __launch_bounds__(1024) void k_coarse(const int* __restrict__ s0,
                                                 const int* __restrict__ s1,
                                                 const int* __restrict__ s2,
                                                 const int* __restrict__ d0,
                                                 const int* __restrict__ d1,
                                                 const int* __restrict__ d2,
                                                 int* __restrict__ curB,
                                                 unsigned* __restrict__ staging) {
  __shared__ int bcnt[NBKT];
  __shared__ int bbase[NBKT];
  int g = blockIdx.y;
  const int* src = (g == 0) ? s0 : (g == 1) ? s1 : s2;
  const int* dst = (g == 0) ? d0 : (g == 1) ? d1 : d2;
  int tid = threadIdx.x;
  if (tid < NBKT) bcnt[tid] = 0;
  __syncthreads();
  int e = blockIdx.x * 1024 + tid;
  bool val = e < NE;
  int b = 0, r = 0, sv = 0, dv = 0;
  if (val) {
    dv = dst[e]; sv = src[e];
    b = dv >> 8;
    r = atomicAdd(&bcnt[b], 1);
  }
  __syncthreads();
  if (tid < NBKT && bcnt[tid] > 0) bbase[tid] = atomicAdd(&curB[g * (NBKT + 1) + tid], bcnt[tid]);
  __syncthreads();
  if (val) staging[(size_t)g * NE + bbase[b] + r] = ((unsigned)sv << 8) | (unsigned)(dv & 255);
}

__global__ __launch_bounds__(1024) void k_fine(const int* __restrict__ rowptr3,
                                               const unsigned* __restrict__ staging,
                                               unsigned short* __restrict__ srcord3) {
  __shared__ int cur[256];
  int g = blockIdx.y, b = blockIdx.x;
  const int* rowptr = rowptr3 + g * (NN + 1);
  int n0 = b << 8;
  int tid = threadIdx.x;
  if (tid < 256) {
    int node = n0 + tid;
    cur[tid] = (node < NN) ? rowptr[node] : 0;
  }
  __syncthreads();
  int nend = n0 + 256; if (nend > NN) nend = NN;
  int start = rowptr[n0];
  int endp = rowptr[nend];
  for (int i = start + tid; i < endp; i += 1024) {
    unsigned u = staging[(size_t)g * NE + i];
    int nl = u & 255;
    int pos = atomicAdd(&cur[nl], 1);
    srcord3[(size_t)g * NE + pos] = (unsigned short)(u >> 8);
  }
}

// ---------------- FUSED softmax + gather aggregation + bias + elu (bf16 out) ----------------
// wave per node; lane = 16B slice of the 512-wide row, head = lane>>3.
__global__ __launch_bounds__(256) void k_aggf(const int* __restrict__ rowptr,
                                              const unsigned short* __restrict__ srcord,
                                              const float* __restrict__ el,
                                              const float* __restrict__ er,
                                              const unsigned short* __restrict__ hb,
                                              const float* __restrict__ bias,
                                              unsigned short* __restrict__ ob) {
  __shared__ float aS[4][64 * 8];
  __shared__ int sS[4][64];
  int wv = threadIdx.x >> 6;
  int t = (blockIdx.x * 256 + threadIdx.x) >> 6;
  int lane = threadIdx.x & 63;
  int h = lane >> 3;
  int beg = rowptr[t], end = rowptr[t + 1];

  float4 er0 = ((const float4*)(er + (size_t)t * NH))[0];
  float4 er1 = ((const float4*)(er + (size_t)t * NH))[1];
  float erow[8] = {er0.x, er0.y, er0.z, er0.w, er1.x, er1.y, er1.z, er1.w};

  float acc[8] = {0.f, 0.f, 0.f, 0.f, 0.f, 0.f, 0.f, 0.f};
  float den = 0.f;

  for (int cbeg = beg; cbeg < end; cbeg += 64) {
    int cnt = end - cbeg; if (cnt > 64) cnt = 64;
    bool valid = lane < cnt;
    int pidx = cbeg + lane; if (pidx > end - 1) pidx = end - 1;
    int s = srcord[pidx];
    if (valid) {
      sS[wv][lane] = s;
      float4 a0 = ((const float4*)(el + (size_t)s * NH))[0];
      float4 a1 = ((const float4*)(el + (size_t)s * NH))[1];
      float v[8] = {a0.x + erow[0], a0.y + erow[1], a0.z + erow[2], a0.w + erow[3],
                    a1.x + erow[4], a1.y + erow[5], a1.z + erow[6], a1.w + erow[7]};
#pragma unroll
      for (int k = 0; k < 8; k++) {
        float x = v[k];
        x = x >= 0.f ? x : 0.2f * x;
        aS[wv][lane * 8 + k] = __expf(x);
      }
    }
    const unsigned short* hbl = hb + lane * 8;
    int q = 0;
    for (; q + 3 < cnt; q += 4) {
      int s0 = sS[wv][q], s1 = sS[wv][q + 1], s2 = sS[wv][q + 2], s3 = sS[wv][q + 3];
      float w0 = aS[wv][q * 8 + h];
      float w1 = aS[wv][(q + 1) * 8 + h];
      float w2 = aS[wv][(q + 2) * 8 + h];
      float w3 = aS[wv][(q + 3) * 8 + h];
      uint4 v0 = *(const uint4*)(hbl + (size_t)s0 * NHD);
      uint4 v1 = *(const uint4*)(hbl + (size_t)s1 * NHD);
      uint4 v2 = *(const uint4*)(hbl + (size_t)s2 * NHD);
      uint4 v3 = *(const uint4*)(hbl + (size_t)s3 * NHD);
      den += (w0 + w1) + (w2 + w3);
      acc[0] += w0 * bflo(v0.x); acc[1] += w0 * bfhi(v0.x);
      acc[2] += w0 * bflo(v0.y); acc[3] += w0 * bfhi(v0.y);
      acc[4] += w0 * bflo(v0.z); acc[5] += w0 * bfhi(v0.z);
      acc[6] += w0 * bflo(v0.w); acc[7] += w0 * bfhi(v0.w);
      acc[0] += w1 * bflo(v1.x); acc[1] += w1 * bfhi(v1.x);
      acc[2] += w1 * bflo(v1.y); acc[3] += w1 * bfhi(v1.y);
      acc[4] += w1 * bflo(v1.z); acc[5] += w1 * bfhi(v1.z);
      acc[6] += w1 * bflo(v1.w); acc[7] += w1 * bfhi(v1.w);
      acc[0] += w2 * bflo(v2.x); acc[1] += w2 * bfhi(v2.x);
      acc[2] += w2 * bflo(v2.y); acc[3] += w2 * bfhi(v2.y);
      acc[4] += w2 * bflo(v2.z); acc[5] += w2 * bfhi(v2.z);
      acc[6] += w2 * bflo(v2.w); acc[7] += w2 * bfhi(v2.w);
      acc[0] += w3 * bflo(v3.x); acc[1] += w3 * bfhi(v3.x);
      acc[2] += w3 * bflo(v3.y); acc[3] += w3 * bfhi(v3.y);
      acc[4] += w3 * bflo(v3.z); acc[5] += w3 * bfhi(v3.z);
      acc[6] += w3 * bflo(v3.w); acc[7] += w3 * bfhi(v3.w);
    }
    for (; q < cnt; q++) {
      int s0 = sS[wv][q];
      float w0 = aS[wv][q * 8 + h];
      uint4 v0 = *(const uint4*)(hbl + (size_t)s0 * NHD);
      den += w0;
      acc[0] += w0 * bflo(v0.x); acc[1] += w0 * bfhi(v0.x);
      acc[2] += w0 * bflo(v0.y); acc[3] += w0 * bfhi(v0.y);
      acc[4] += w0 * bflo(v0.z); acc[5] += w0 * bfhi(v0.z);
      acc[6] += w0 * bflo(v0.w); acc[7] += w0 * bfhi(v0.w);
    }
  }

  float dn = 1.f / fmaxf(den, 1e-9f);
  float4 b0 = ((const float4*)(bias + lane * 8))[0];
  float4 b1 = ((const float4*)(bias + lane * 8))[1];
  float r[8];
  r[0] = acc[0] * dn + b0.x; r[1] = acc[1] * dn + b0.y;
  r[2] = acc[2] * dn + b0.z; r[3] = acc[3] * dn + b0.w;
  r[4] = acc[4] * dn + b1.x; r[5] = acc[5] * dn + b1.y;
  r[6] = acc[6] * dn + b1.z; r[7] = acc[7] * dn + b1.w;
#pragma unroll
  for (int j = 0; j < 8; j++) r[j] = r[j] > 0.f ? r[j] : expm1f(r[j]);
  uint4 z;
  z.x = ((unsigned)f2bf(r[1]) << 16) | f2bf(r[0]);
  z.y = ((unsigned)f2bf(r[3]) << 16) | f2bf(r[2]);
  z.z = ((unsigned)f2bf(r[5]) << 16) | f2bf(r[4]);
  z.w = ((unsigned)f2bf(r[7]) << 16) | f2bf(r[6]);
  *(uint4*)(ob + (size_t)t * NHD + lane * 8) = z;
}

// stage 1: sound(bf16) = beta0*zA(bf16) + beta1*zB(bf16)
__global__ void k_combine_s1(const float* __restrict__ scal,
                             const unsigned short* __restrict__ zA,
                             const unsigned short* __restrict__ zB,
                             unsigned short* __restrict__ outb) {
  int i = blockIdx.x * 256 + threadIdx.x;   // grid exact CC*NHD/4
  float w0 = scal[0] * (1.f / CC), w1v = scal[1] * (1.f / CC);
  float mx = fmaxf(w0, w1v);
  float e0 = expf(w0 - mx), e1 = expf(w1v - mx);
  float inv = 1.f / (e0 + e1);
  float b0 = e0 * inv, b1v = e1 * inv;
  ushort4 a = ((const ushort4*)zA)[i];
  ushort4 b = ((const ushort4*)zB)[i];
  ushort4 z;
  z.x = f2bf(b0 * bf2f(a.x) + b1v * bf2f(b.x));
  z.y = f2bf(b0 * bf2f(a.y) + b1v * bf2f(b.y));
  z.z = f2bf(b0 * bf2f(a.z) + b1v * bf2f(b.z));
  z.w = f2bf(b0 * bf2f(a.w) + b1v * bf2f(b.w));
  ((ushort4*)outb)[i] = z;
}

// ---------------- fused stage-2 combine + final head-means (bf16 inputs) ----------------
__global__ void k_comb2_means(const float* __restrict__ scal,
                              const unsigned short* __restrict__ zsound,
                              const unsigned short* __restrict__ ob0,
                              const unsigned short* __restrict__ ob1,
                              const unsigned short* __restrict__ ob2,
                              float* __restrict__ outf,
                              float* __restrict__ m1, float* __restrict__ m2,
                              float* __restrict__ m3) {
  int idx = blockIdx.x * 256 + threadIdx.x;   // grid exact NN*64
  int n = idx >> 6, d = idx & 63;
  if (n < CC) {
    float w0 = scal[0] * (1.f / CC), w1v = scal[1] * (1.f / CC);
    float mx = fmaxf(w0, w1v);
    float e0 = expf(w0 - mx), e1 = expf(w1v - mx);
    float inv = 1.f / (e0 + e1);
    float b0 = e0 * inv, b1v = e1 * inv;
    const unsigned short* zs = zsound + (size_t)n * NHD + d;
    const unsigned short* p1 = ob1 + (size_t)n * NHD + d;
    float* po = outf + (size_t)n * NHD + d;
    float v = 0.f;
#pragma unroll
    for (int h = 0; h < 8; h++) {
      float r = b0 * bf2f(zs[h * 64]) + b1v * bf2f(p1[h * 64]);
      po[h * 64] = r;
      v += r;
    }
    v *= 0.125f;
    m1[idx] = v; m2[idx] = v; m3[idx] = v;
  } else {
    const unsigned short* p0 = ob0 + (size_t)n * NHD + d;
    const unsigned short* p1 = ob1 + (size_t)n * NHD + d;
    const unsigned short* p2 = ob2 + (size_t)n * NHD + d;
    float v0 = 0.f, v1 = 0.f, v2 = 0.f;
#pragma unroll
    for (int h = 0; h < 8; h++) {
      v0 += bf2f(p0[h * 64]); v1 += bf2f(p1[h * 64]); v2 += bf2f(p2[h * 64]);
    }
    m1[idx] = v0 * 0.125f; m2[idx] = v1 * 0.125f; m3[idx] = v2 * 0.125f;
  }
}

extern "C" void kernel_launch(void* const* d_in, const int* in_sizes, int n_in,
                              void* d_out, int out_size, void* d_ws, size_t ws_size,
                              hipStream_t stream) {
  (void)in_sizes; (void)n_in; (void)out_size; (void)ws_size;

  const float* feat[3]; const int* srcp[3]; const int* dstp[3];
  const float* Wp[3]; const float* alp[3]; const float* arp[3]; const float* bp[3];
  for (int g = 0; g < 3; g++) {
    const int base = g * 8;  // dict order: feat,src,dst,char,W,al,ar,b
    feat[g] = (const float*)d_in[base + 0];
    srcp[g] = (const int*)d_in[base + 1];
    dstp[g] = (const int*)d_in[base + 2];
    Wp[g]   = (const float*)d_in[base + 4];
    alp[g]  = (const float*)d_in[base + 5];
    arp[g]  = (const float*)d_in[base + 6];
    bp[g]   = (const float*)d_in[base + 7];
  }
  const float* sw1 = (const float*)d_in[24];
  const float* sb1 = (const float*)d_in[25];
  const float* sw2 = (const float*)d_in[26];
  const float* aw1 = (const float*)d_in[27];
  const float* ab1 = (const float*)d_in[28];
  const float* aw2 = (const float*)d_in[29];

  char* wsp = (char*)d_ws;
  auto alloc = [&](size_t bytes) {
    char* p = wsp;
    wsp += (bytes + 255) & ~(size_t)255;
    return p;
  };
  // total ~103 MB
  unsigned short* ob0 = (unsigned short*)alloc((size_t)NN * NHD * 2);
  unsigned short* ob1 = (unsigned short*)alloc((size_t)NN * NHD * 2);
  unsigned short* ob2 = (unsigned short*)alloc((size_t)NN * NHD * 2);
  unsigned short* hb = (unsigned short*)alloc((size_t)NN * NHD * 2);
  unsigned short* wtb3 = (unsigned short*)alloc((size_t)3 * WTB_SZ * 2);
  unsigned short* w1tb2 = (unsigned short*)alloc((size_t)2 * W1TB_SZ * 2);
  unsigned short* sound = (unsigned short*)alloc((size_t)CC * NHD * 2);
  float* el = (float*)alloc((size_t)NN * NH * 4);
  float* er = (float*)alloc((size_t)NN * NH * 4);
  float* scal = (float*)alloc(256);
  int* deg3 = (int*)alloc((size_t)3 * NN * 4);
  int* rowptr3 = (int*)alloc((size_t)3 * (NN + 1) * 4 + 64);
  int* curB = (int*)alloc((size_t)3 * (NBKT + 1) * 4);
  unsigned* staging = (unsigned*)alloc((size_t)3 * NE * 4);
  unsigned short* srcord3 = (unsigned short*)alloc((size_t)3 * NE * 2);

  float* outf = (float*)d_out;
  float* outm1 = outf + (size_t)CC * NHD;
  float* outm2 = outm1 + (size_t)NN * ND;
  float* outm3 = outm2 + (size_t)NN * ND;

  // ---- prep: weight transposes + zero deg3/scal; bucket-staged CSR build ----
  const int PREP_T = 3 * WTB_SZ + 2 * W1TB_SZ + 3 * NN + 4;
  k_prep<<<(PREP_T + 255) / 256, 256, 0, stream>>>(Wp[0], Wp[1], Wp[2], sw1, aw1,
                                                   wtb3, w1tb2, deg3, scal);
  k_hist3<<<dim3(NE / 256, 3), 256, 0, stream>>>(dstp[0], dstp[1], dstp[2], deg3);
  k_scan3<<<3, 1024, 0, stream>>>(deg3, rowptr3, curB);
  k_coarse<<<dim3((NE + 1023) / 1024, 3), 1024, 0, stream>>>(
      srcp[0], srcp[1], srcp[2], dstp[0], dstp[1], dstp[2], curB, staging);
  k_fine<<<dim3(NBKT, 3), 1024, 0, stream>>>(rowptr3, staging, srcord3);

  // one full GAT layer for metapath g -> bf16 ob (feat read f32, cast inline in GEMM)
  // gemm grid: 20 row-groups x 4 col-tiles x 8 XCDs = 640 linear blocks
  auto gat = [&](int g, unsigned short* ob) {
    k_gemm_gat<<<640, 256, 0, stream>>>(
        feat[g], wtb3 + (size_t)g * WTB_SZ, hb, alp[g], arp[g], el, er);
    k_aggf<<<NN * 64 / 256, 256, 0, stream>>>(rowptr3 + g * (NN + 1), srcord3 + (size_t)g * NE,
                                              el, er, hb, bp[g], ob);
  };

  gat(0, ob0);
  gat(2, ob2);

  // ---- semantic stage 1: rows<CC from ob0, rows>=CC from ob2 -> sound ----
  k_gemm_sem<<<(2 * CC + 127) / 128, 256, 0, stream>>>(ob0, ob2, w1tb2, sb1, sw2, scal);
  k_combine_s1<<<CC * NHD / 4 / 256, 256, 0, stream>>>(scal, ob0, ob2, sound);

  gat(1, ob1);

  // ---- semantic stage 2: rows<CC from sound, rows>=CC from ob1 -> combine+means ----
  k_gemm_sem<<<(2 * CC + 127) / 128, 256, 0, stream>>>(sound, ob1, w1tb2 + W1TB_SZ, ab1, aw2, scal + 2);
  k_comb2_means<<<NN * 64 / 256, 256, 0, stream>>>(scal + 2, sound, ob0, ob1, ob2,
                                                   outf, outm1, outm2, outm3);
}